// Round 9
// baseline (517.691 us; speedup 1.0000x reference)
//
#include <hip/hip_runtime.h>

typedef unsigned short ushort_t;
typedef __attribute__((ext_vector_type(8))) __bf16 bf16x8;
typedef __attribute__((ext_vector_type(4))) float f32x4;

__device__ __forceinline__ float bf2f(ushort_t u) {
    union { unsigned int i; float f; } v; v.i = ((unsigned int)u) << 16; return v.f;
}
__device__ __forceinline__ ushort_t f2bf(float f) {
    union { float f; unsigned int i; } v; v.f = f;
    unsigned int r = (v.i + 0x7FFFu + ((v.i >> 16) & 1u)) >> 16;
    return (ushort_t)r;
}
__device__ __forceinline__ float gelu_exact(float v) {
    return 0.5f * v * (1.f + erff(v * 0.70710678118654752f));
}
__device__ __forceinline__ float ld1(const void* p, size_t i, int isf32) {
    return isf32 ? ((const float*)p)[i] : bf2f(((const ushort_t*)p)[i]);
}
__device__ __forceinline__ void stage8(const void* p, size_t idx, int isf32, ushort_t* dst) {
    if (isf32) {
        const float* f = (const float*)p + idx;
        float4 u = *(const float4*)f;
        float4 v = *(const float4*)(f + 4);
        dst[0] = f2bf(u.x); dst[1] = f2bf(u.y); dst[2] = f2bf(u.z); dst[3] = f2bf(u.w);
        dst[4] = f2bf(v.x); dst[5] = f2bf(v.y); dst[6] = f2bf(v.z); dst[7] = f2bf(v.w);
    } else {
        *(uint4*)dst = *(const uint4*)((const ushort_t*)p + idx);
    }
}
// async global->LDS, 16B per lane; LDS dest must be wave-uniform base (HW adds lane*16)
__device__ __forceinline__ void gload16(const ushort_t* g, ushort_t* l) {
    __builtin_amdgcn_global_load_lds(
        (const __attribute__((address_space(1))) unsigned int*)g,
        (__attribute__((address_space(3))) unsigned int*)l, 16, 0, 0);
}

// scatter stores into attention-layout buffers
__device__ __forceinline__ void store_q(ushort_t* qbuf, int row, int c, int p0, float v) {
    int b = row >> 9, t = row & 511;
    qbuf[((((size_t)(b * 16 + (c >> 6))) * 4 + p0) * 512 + t) * 64 + (c & 63)] = f2bf(v);
}
__device__ __forceinline__ void store_k(ushort_t* kbuf, int row, int c, int koff, int p1, float v) {
    int b = row >> p1, t = row & ((1 << p1) - 1);
    kbuf[(((size_t)(b * 16 + (c >> 6))) * 1792 + koff + t) * 64 + (c & 63)] = f2bf(v);
}
__device__ __forceinline__ void store_v(ushort_t* vbufT, int row, int c, int koff, int p1, float v) {
    int b = row >> p1, t = row & ((1 << p1) - 1);
    vbufT[(((size_t)(b * 16 + (c >> 6))) * 64 + (c & 63)) * 1792 + koff + t] = f2bf(v);
}

__global__ void detect_kernel(const unsigned int* __restrict__ x, int* __restrict__ flag) {
    if (threadIdx.x == 0 && blockIdx.x == 0) {
        int sane = 0;
        for (int i = 0; i < 256; i++) {
            unsigned int e = (x[i] >> 7) & 0xFFu;
            if (e == 0u || (e >= 100u && e <= 140u)) sane++;
        }
        *flag = (sane >= 200) ? 0 : 1;
    }
}

// precompute RoPE cos/sin table: [t=0..511][d31=0..31] -> (cos, sin) pairs
__global__ void prep_rope_kernel(float* __restrict__ tab) {
    int idx = blockIdx.x * 256 + threadIdx.x;    // 0..16383
    int t = idx >> 5, d = idx & 31;
    float ang = (float)t * __expf(-(float)d * (9.210340371976184f / 32.f));
    float cs, sn;
    sincosf(ang, &sn, &cs);
    tab[idx * 2]     = cs;
    tab[idx * 2 + 1] = sn;
}

// weight cache layout (elements) — adaln NOT cached (read directly by adaln_kernel)
static constexpr size_t CW_QPROJ = 0;          // 1024x1024
static constexpr size_t CW_QA    = 1048576;    // 3x256x1024
static constexpr size_t CW_QAOUT = 1835008;    // 1024x256
static constexpr size_t CW_KW    = 2097152;    // 4x1024x1024
static constexpr size_t CW_VW    = 6291456;    // 4x1024x1024
static constexpr size_t CW_OW    = 10485760;   // 1024x1024
static constexpr size_t CW_FFN1  = 11534336;   // 4096x1024
static constexpr size_t CW_FFN2  = 15728640;   // 1024x4096
static constexpr size_t CW_TOTAL = 19922944;   // elements (x2 bytes = 39.8 MB)

__global__ void __launch_bounds__(256) convert_weights_kernel(
    const void* s0, const void* s1, const void* s2, const void* s3,
    const void* s4, const void* s5, const void* s6, const void* s7,
    ushort_t* __restrict__ dst, const int* __restrict__ dflag) {
    int isf32 = *dflag;
    size_t i8 = ((size_t)blockIdx.x * 256 + threadIdx.x) * 8;
    if (i8 >= CW_TOTAL) return;
    const void* src; size_t base;
    if      (i8 < CW_QA)    { src = s0; base = CW_QPROJ; }
    else if (i8 < CW_QAOUT) { src = s1; base = CW_QA; }
    else if (i8 < CW_KW)    { src = s2; base = CW_QAOUT; }
    else if (i8 < CW_VW)    { src = s3; base = CW_KW; }
    else if (i8 < CW_OW)    { src = s4; base = CW_VW; }
    else if (i8 < CW_FFN1)  { src = s5; base = CW_OW; }
    else if (i8 < CW_FFN2)  { src = s6; base = CW_FFN1; }
    else                    { src = s7; base = CW_FFN2; }
    ushort_t t8[8];
    stage8(src, i8 - base, isf32, t8);
    *(uint4*)(dst + i8) = *(uint4*)t8;
}

// bev(2048 rows) + vl(2048 rows) -> actA; reas(1024 rows) -> actB. All x1024 cols.
__global__ void __launch_bounds__(256) convert_act3_kernel(
    const void* __restrict__ bev, const void* __restrict__ vl,
    const void* __restrict__ reas, ushort_t* __restrict__ actA,
    ushort_t* __restrict__ actB, const int* __restrict__ dflag) {
    int isf32 = *dflag;
    size_t i8 = ((size_t)blockIdx.x * 256 + threadIdx.x) * 8;
    if (i8 >= 5242880) return;
    ushort_t t8[8];
    if (i8 < 2097152) {
        stage8(bev, i8, isf32, t8);
        *(uint4*)(actA + i8) = *(uint4*)t8;
    } else if (i8 < 4194304) {
        stage8(vl, i8 - 2097152, isf32, t8);
        *(uint4*)(actA + i8) = *(uint4*)t8;
    } else {
        stage8(reas, i8 - 4194304, isf32, t8);
        *(uint4*)(actB + (i8 - 4194304)) = *(uint4*)t8;
    }
}

__global__ void prep_consts_kernel(const void* __restrict__ temps,
                                   const void* __restrict__ biases,
                                   const void* __restrict__ gating,
                                   float* __restrict__ consts,
                                   const int* __restrict__ dflag) {
    if (threadIdx.x == 0 && blockIdx.x == 0) {
        int isf32 = *dflag;
        float g = tanhf(ld1(gating, 0, isf32));
        for (int s = 0; s < 4; s++) {
            float t  = ld1(temps, s, isf32);
            float sp = (t > 20.f) ? t : log1pf(expf(t));
            float scale = 0.125f * (1.f + sp);
            float mul = (s == 3) ? g : 1.f;
            consts[s]     = scale * mul;
            consts[4 + s] = ld1(biases, s, isf32) * mul;
        }
    }
}

// mod = bias (broadcast over the 4 batches); adaln_kernel atomically adds partials
__global__ void adaln_init_kernel(const void* __restrict__ bias, float* __restrict__ mod,
                                  const int* __restrict__ dflag) {
    int isf32 = *dflag;
    int n = blockIdx.x * 256 + threadIdx.x;      // 0..6143
    float b = ld1(bias, n, isf32);
    #pragma unroll
    for (int bb = 0; bb < 4; bb++) mod[(size_t)bb * 6144 + n] = b;
}

// grid (24, 4, 4): z splits the 1024-d dot into 4 chunks of 256; partials
// atomicAdd into mod (pre-initialized with bias). 384 blocks vs 96 before.
__global__ void __launch_bounds__(256) adaln_kernel(
    const void* __restrict__ cond, const void* __restrict__ w,
    float* __restrict__ mod, const int* __restrict__ dflag) {
    __shared__ float cs[256];
    int isf32 = *dflag;
    int b = blockIdx.y, z = blockIdx.z, tid = threadIdx.x;
    {
        float c = ld1(cond, b * 1024 + z * 256 + tid, isf32);
        cs[tid] = c / (1.f + expf(-c));
    }
    __syncthreads();
    int n = blockIdx.x * 256 + tid;
    float acc = 0.f;
    if (isf32) {
        const float* wr = (const float*)w + (size_t)n * 1024 + z * 256;
        for (int d = 0; d < 256; d += 8) {
            float4 a = *(const float4*)(wr + d);
            float4 bb = *(const float4*)(wr + d + 4);
            acc += cs[d+0]*a.x + cs[d+1]*a.y + cs[d+2]*a.z + cs[d+3]*a.w
                 + cs[d+4]*bb.x + cs[d+5]*bb.y + cs[d+6]*bb.z + cs[d+7]*bb.w;
        }
    } else {
        const ushort_t* wr = (const ushort_t*)w + (size_t)n * 1024 + z * 256;
        for (int d = 0; d < 256; d += 8) {
            uint4 raw = *(const uint4*)(wr + d);
            const ushort_t* u = (const ushort_t*)&raw;
            acc += cs[d+0]*bf2f(u[0]) + cs[d+1]*bf2f(u[1]) + cs[d+2]*bf2f(u[2]) + cs[d+3]*bf2f(u[3])
                 + cs[d+4]*bf2f(u[4]) + cs[d+5]*bf2f(u[5]) + cs[d+6]*bf2f(u[6]) + cs[d+7]*bf2f(u[7]);
        }
    }
    atomicAdd(&mod[(size_t)b * 6144 + n], acc);
}

template <int SRC>
__global__ void __launch_bounds__(256) ln_mod_kernel(
    const void* __restrict__ xin, const float* __restrict__ mod,
    const void* __restrict__ lnw, const void* __restrict__ lnb,
    int shift_off, int scale_off, ushort_t* __restrict__ out,
    const int* __restrict__ dflag) {
    int isf32 = *dflag;
    int row = blockIdx.x, tid = threadIdx.x;
    int b = row >> 9;
    float v[4];
    #pragma unroll
    for (int i = 0; i < 4; i++) {
        size_t idx = (size_t)row * 1024 + tid + 256 * i;
        v[i] = (SRC == 1) ? ((const float*)xin)[idx] : ld1(xin, idx, isf32);
    }
    float s = v[0] + v[1] + v[2] + v[3];
    float ss = v[0]*v[0] + v[1]*v[1] + v[2]*v[2] + v[3]*v[3];
    #pragma unroll
    for (int off = 1; off < 64; off <<= 1) {
        s  += __shfl_xor(s,  off, 64);
        ss += __shfl_xor(ss, off, 64);
    }
    __shared__ float red[8];
    int w = tid >> 6;
    if ((tid & 63) == 0) { red[w] = s; red[4 + w] = ss; }
    __syncthreads();
    s  = red[0] + red[1] + red[2] + red[3];
    ss = red[4] + red[5] + red[6] + red[7];
    float mean = s * (1.f / 1024.f);
    float var  = ss * (1.f / 1024.f) - mean * mean;
    float inv  = rsqrtf(var + 1e-5f);
    const float* mb = mod + (size_t)b * 6144;
    #pragma unroll
    for (int i = 0; i < 4; i++) {
        int d = tid + 256 * i;
        float xn = (v[i] - mean) * inv;
        float y  = xn * ld1(lnw, d, isf32) + ld1(lnb, d, isf32);
        out[(size_t)row * 1024 + d] = f2bf(y * (1.f + mb[scale_off + d]) + mb[shift_off + d]);
    }
}

// Fused residual-gate + FFN LayerNorm: one block per row. Computes
// x1 = x + gate*proj (stored f32 for the final residual) then LN+mod -> hin.
__global__ void __launch_bounds__(256) resgate_ln_kernel(
    const void* __restrict__ x, const float* __restrict__ p0,
    const float* __restrict__ p1, const float* __restrict__ p2,
    const float* __restrict__ p3, const float* __restrict__ mod,
    const void* __restrict__ lnw, const void* __restrict__ lnb,
    float* __restrict__ x1, ushort_t* __restrict__ hin,
    const int* __restrict__ dflag) {
    int isf32 = *dflag;
    int row = blockIdx.x, tid = threadIdx.x;
    int b = row >> 9;
    const float* mb = mod + (size_t)b * 6144;
    float v[4];
    #pragma unroll
    for (int i = 0; i < 4; i++) {
        size_t idx = (size_t)row * 1024 + tid + 256 * i;
        int n = tid + 256 * i;
        float proj = p0[idx] + p1[idx] + p2[idx] + p3[idx];
        v[i] = ld1(x, idx, isf32) + mb[2048 + n] * proj;
        x1[idx] = v[i];
    }
    float s = v[0] + v[1] + v[2] + v[3];
    float ss = v[0]*v[0] + v[1]*v[1] + v[2]*v[2] + v[3]*v[3];
    #pragma unroll
    for (int off = 1; off < 64; off <<= 1) {
        s  += __shfl_xor(s,  off, 64);
        ss += __shfl_xor(ss, off, 64);
    }
    __shared__ float red[8];
    int w = tid >> 6;
    if ((tid & 63) == 0) { red[w] = s; red[4 + w] = ss; }
    __syncthreads();
    s  = red[0] + red[1] + red[2] + red[3];
    ss = red[4] + red[5] + red[6] + red[7];
    float mean = s * (1.f / 1024.f);
    float var  = ss * (1.f / 1024.f) - mean * mean;
    float inv  = rsqrtf(var + 1e-5f);
    #pragma unroll
    for (int i = 0; i < 4; i++) {
        int d = tid + 256 * i;
        float xn = (v[i] - mean) * inv;
        float y  = xn * ld1(lnw, d, isf32) + ld1(lnb, d, isf32);
        hin[(size_t)row * 1024 + d] = f2bf(y * (1.f + mb[4096 + d]) + mb[3072 + d]);
    }
}

// ---------------------------------------------------------------------------
// Legacy 64x64 GEMM kept ONLY for the no-weight-cache fallback path.
// ---------------------------------------------------------------------------
template <int EPI>
__global__ void __launch_bounds__(256) gemm_bt_kernel(
    const void* __restrict__ A, int lda,
    const void* __restrict__ W, int wrow0,
    const void* __restrict__ bias,
    void* __restrict__ Cout, int ldc, int K, int p0, int p1,
    int a_ext, int wmode, const int* __restrict__ dflag) {
    __shared__ ushort_t As[64][40];
    __shared__ ushort_t Bs[64][40];
    int isf32 = *dflag;
    int fa = a_ext ? isf32 : 0;
    int fw = (wmode == 2) ? 0 : isf32;
    int m0 = blockIdx.x * 64, n0 = blockIdx.y * 64;
    int tid = threadIdx.x;
    int r = tid >> 2, c = (tid & 3) * 8;
    int w = tid >> 6, ln = tid & 63;
    int msub = (w & 1) * 32, nsub = (w >> 1) * 32;
    int fr = ln & 15, q = ln >> 4;
    f32x4 acc00 = {0.f,0.f,0.f,0.f}, acc01 = {0.f,0.f,0.f,0.f};
    f32x4 acc10 = {0.f,0.f,0.f,0.f}, acc11 = {0.f,0.f,0.f,0.f};
    for (int k0 = 0; k0 < K; k0 += 32) {
        __syncthreads();
        {
            ushort_t t8[8];
            stage8(A, (size_t)(m0 + r) * lda + c + k0, fa, t8);
            *(uint4*)&As[r][c] = *(uint4*)t8;
        }
        {
            ushort_t t8[8];
            stage8(W, (size_t)(wrow0 + n0 + r) * K + c + k0, fw, t8);
            *(uint4*)&Bs[r][c] = *(uint4*)t8;
        }
        __syncthreads();
        bf16x8 a0 = *(const bf16x8*)&As[msub + fr][q * 8];
        bf16x8 a1 = *(const bf16x8*)&As[msub + 16 + fr][q * 8];
        bf16x8 b0 = *(const bf16x8*)&Bs[nsub + fr][q * 8];
        bf16x8 b1 = *(const bf16x8*)&Bs[nsub + 16 + fr][q * 8];
        acc00 = __builtin_amdgcn_mfma_f32_16x16x32_bf16(a0, b0, acc00, 0, 0, 0);
        acc01 = __builtin_amdgcn_mfma_f32_16x16x32_bf16(a0, b1, acc01, 0, 0, 0);
        acc10 = __builtin_amdgcn_mfma_f32_16x16x32_bf16(a1, b0, acc10, 0, 0, 0);
        acc11 = __builtin_amdgcn_mfma_f32_16x16x32_bf16(a1, b1, acc11, 0, 0, 0);
    }
    int col0 = n0 + nsub + fr;
    float bv0 = ld1(bias, wrow0 + col0, isf32);
    float bv1 = ld1(bias, wrow0 + col0 + 16, isf32);
    #pragma unroll
    for (int mi = 0; mi < 2; mi++) {
        #pragma unroll
        for (int ni = 0; ni < 2; ni++) {
            f32x4 a = (mi == 0) ? (ni == 0 ? acc00 : acc01) : (ni == 0 ? acc10 : acc11);
            int col = col0 + ni * 16;
            float bb = (ni == 0) ? bv0 : bv1;
            #pragma unroll
            for (int e = 0; e < 4; e++) {
                int rowg = m0 + msub + mi * 16 + q * 4 + e;
                float v = a[e] + bb;
                if (EPI == 2) v = gelu_exact(v);
                if (EPI == 0) {
                    ((float*)Cout)[(size_t)rowg * ldc + col] = v;
                } else if (EPI == 1 || EPI == 2) {
                    ((ushort_t*)Cout)[(size_t)rowg * ldc + col] = f2bf(v);
                } else if (EPI == 3) {
                    store_k((ushort_t*)Cout, rowg, col, p0, p1, v);
                } else if (EPI == 5) {
                    store_v((ushort_t*)Cout, rowg, col, p0, p1, v);
                } else {  // EPI == 4
                    store_q((ushort_t*)Cout, rowg, col, p0, v);
                }
            }
        }
    }
}

// ---------------------------------------------------------------------------
// m97-structure GEMM mainloop (known-good BK=32): 128x128 tile, 4 waves,
// single-buffered 16 KB LDS, global_load_lds width-16 staging, 16 MFMA +
// 8 ds_read_b128 per K-step/wave, 2 barriers per K-step. ~8 blocks/CU.
// ---------------------------------------------------------------------------
__device__ __forceinline__ void gemm_mainloop(
    const ushort_t* __restrict__ A, int lda,
    const ushort_t* __restrict__ W, int ldw,
    int m0, int wrow0, int kbeg, int klen,
    ushort_t* As, ushort_t* Bs, f32x4 acc[4][4])
{
    const int tid = threadIdx.x;
    const int w = tid >> 6;
    const int ln = tid & 63;
    const int fr = ln & 15, q = ln >> 4;
    const int wm = w & 1, wn = w >> 1;
    const ushort_t* gA = A + (size_t)(m0 + (tid >> 2)) * lda + kbeg + (tid & 3) * 8;
    const ushort_t* gW = W + (size_t)(wrow0 + (tid >> 2)) * ldw + kbeg + (tid & 3) * 8;
    const size_t sA = (size_t)64 * lda;
    const size_t sW = (size_t)64 * ldw;
    ushort_t* lA = As + w * 512;     // wave-uniform LDS dest (rows 16w..16w+15)
    ushort_t* lB = Bs + w * 512;
    for (int k = 0; k < klen; k += 32) {
        __syncthreads();                          // prev compute done reading LDS
        gload16(gA, lA);                          // rows 0..63 of the 128x32 tile
        gload16(gA + sA, lA + 2048);              // rows 64..127
        gload16(gW, lB);
        gload16(gW + sW, lB + 2048);
        gA += 32; gW += 32;
        __syncthreads();                          // vmcnt(0) drained before barrier
        bf16x8 af[4], bfr[4];
        #pragma unroll
        for (int mi = 0; mi < 4; mi++)
            af[mi] = *(const bf16x8*)&As[(wm * 64 + mi * 16 + fr) * 32 + q * 8];
        #pragma unroll
        for (int ni = 0; ni < 4; ni++)
            bfr[ni] = *(const bf16x8*)&Bs[(wn * 64 + ni * 16 + fr) * 32 + q * 8];
        #pragma unroll
        for (int mi = 0; mi < 4; mi++)
            #pragma unroll
            for (int ni = 0; ni < 4; ni++)
                acc[mi][ni] = __builtin_amdgcn_mfma_f32_16x16x32_bf16(af[mi], bfr[ni], acc[mi][ni], 0, 0, 0);
    }
}

// ---------------------------------------------------------------------------
// Merged stage-1 GEMM with FUSED RMS-norm + RoPE epilogues.
// blocks 0..479: q_proj|qa|K0|V0 over xnorm; 480..1119: cross-source K/V.
// ---------------------------------------------------------------------------
__global__ void __launch_bounds__(256) gemm_stage1_kernel(
    const ushort_t* __restrict__ xnorm,
    const ushort_t* __restrict__ actA, const ushort_t* __restrict__ actB,
    const ushort_t* __restrict__ Wq, const ushort_t* __restrict__ Wqa,
    const ushort_t* __restrict__ Wk, const ushort_t* __restrict__ Wv,
    const void* __restrict__ bq, const void* __restrict__ bqa,
    const void* __restrict__ bk, const void* __restrict__ bv,
    const void* __restrict__ qnw, const void* __restrict__ knw,
    const float* __restrict__ ropetab,
    ushort_t* __restrict__ qbuf, ushort_t* __restrict__ qah,
    ushort_t* __restrict__ kbuf, ushort_t* __restrict__ vbufT,
    const int* __restrict__ dflag)
{
    __shared__ ushort_t As[4096], Bs[4096];
    int isf32 = *dflag;
    int bid = blockIdx.x;
    int mode, koff = 0, p1 = 9, srow0, wrow0, am0, boff = 0;
    const ushort_t* A;
    const ushort_t* W;
    const void* bias;
    if (bid < 480) {
        int bx = bid % 16, by = bid / 16;
        am0 = bx * 128; srow0 = am0;
        int n0 = by * 128;
        A = xnorm;
        if (n0 < 1024)      { mode = 0; W = Wq;  bias = bq;  wrow0 = n0; }
        else if (n0 < 1792) { mode = 1; W = Wqa; bias = bqa; wrow0 = n0 - 1024; }
        else if (n0 < 2816) { mode = 2; W = Wk;  bias = bk;  wrow0 = n0 - 1792; }
        else                { mode = 3; W = Wv;  bias = bv;  wrow0 = n0 - 2816; }
    } else {
        int id2 = bid - 480;               // 0..639
        int mb = id2 % 40, ny = id2 / 40;
        int src;
        if (mb < 16)      { src = 0; A = actA; am0 = mb * 128;        srow0 = am0;             koff = 512;  p1 = 9; }
        else if (mb < 32) { src = 1; A = actA; am0 = mb * 128;        srow0 = (mb - 16) * 128; koff = 1024; p1 = 9; }
        else              { src = 2; A = actB; am0 = (mb - 32) * 128; srow0 = am0;             koff = 1536; p1 = 8; }
        int n0 = ny * 128;
        int isK = (n0 < 1024);
        wrow0 = isK ? n0 : n0 - 1024;
        W = (isK ? Wk : Wv) + (size_t)(src + 1) * 1048576;
        bias = isK ? bk : bv;
        boff = (src + 1) * 1024;
        mode = isK ? 2 : 3;
    }
    f32x4 acc[4][4];
    #pragma unroll
    for (int i = 0; i < 4; i++)
        #pragma unroll
        for (int j = 0; j < 4; j++) acc[i][j] = (f32x4){0.f, 0.f, 0.f, 0.f};
    gemm_mainloop(A, 1024, W, 1024, am0, wrow0, 0, 1024, As, Bs, acc);
    int tid = threadIdx.x, w = tid >> 6, ln = tid & 63;
    int fr = ln & 15, q = ln >> 4;
    int wm = w & 1, wn = w >> 1;
    float bb[4], nw[4];
    #pragma unroll
    for (int ni = 0; ni < 4; ni++)
        bb[ni] = ld1(bias, boff + wrow0 + wn * 64 + ni * 16 + fr, isf32);
    if (mode == 0 || mode == 2) {
        const void* nwp = (mode == 0) ? qnw : knw;
        #pragma unroll
        for (int ni = 0; ni < 4; ni++) nw[ni] = ld1(nwp, ni * 16 + fr, isf32);
    }
    const int tmask = (1 << p1) - 1;
    #pragma unroll
    for (int mi = 0; mi < 4; mi++) {
        #pragma unroll
        for (int e = 0; e < 4; e++) {
            int row = srow0 + wm * 64 + mi * 16 + q * 4 + e;
            float v0 = acc[mi][0][e] + bb[0];
            float v1 = acc[mi][1][e] + bb[1];
            float v2 = acc[mi][2][e] + bb[2];
            float v3 = acc[mi][3][e] + bb[3];
            int c0 = wrow0 + wn * 64 + fr;
            if (mode == 1) {
                qah[(size_t)row * 768 + c0]      = f2bf(v0);
                qah[(size_t)row * 768 + c0 + 16] = f2bf(v1);
                qah[(size_t)row * 768 + c0 + 32] = f2bf(v2);
                qah[(size_t)row * 768 + c0 + 48] = f2bf(v3);
            } else if (mode == 3) {
                store_v(vbufT, row, c0,      koff, p1, v0);
                store_v(vbufT, row, c0 + 16, koff, p1, v1);
                store_v(vbufT, row, c0 + 32, koff, p1, v2);
                store_v(vbufT, row, c0 + 48, koff, p1, v3);
            } else {
                float ss = v0*v0 + v1*v1 + v2*v2 + v3*v3;
                ss += __shfl_xor(ss, 1, 64);
                ss += __shfl_xor(ss, 2, 64);
                ss += __shfl_xor(ss, 4, 64);
                ss += __shfl_xor(ss, 8, 64);
                float inv = rsqrtf(ss * (1.f / 64.f) + 1e-6f);
                float y0 = v0 * inv * nw[0];
                float y1 = v1 * inv * nw[1];
                float y2 = v2 * inv * nw[2];
                float y3 = v3 * inv * nw[3];
                int t = row & tmask;
                float2 cs0 = *(const float2*)&ropetab[((t << 5) + fr) * 2];
                float2 cs1 = *(const float2*)&ropetab[((t << 5) + 16 + fr) * 2];
                float r0 = y0 * cs0.x - y2 * cs0.y;
                float r1 = y1 * cs1.x - y3 * cs1.y;
                float r2 = y2 * cs0.x + y0 * cs0.y;
                float r3 = y3 * cs1.x + y1 * cs1.y;
                if (mode == 0) {
                    store_q(qbuf, row, c0,      0, r0);
                    store_q(qbuf, row, c0 + 16, 0, r1);
                    store_q(qbuf, row, c0 + 32, 0, r2);
                    store_q(qbuf, row, c0 + 48, 0, r3);
                } else {
                    store_k(kbuf, row, c0,      koff, p1, r0);
                    store_k(kbuf, row, c0 + 16, koff, p1, r1);
                    store_k(kbuf, row, c0 + 32, koff, p1, r2);
                    store_k(kbuf, row, c0 + 48, koff, p1, r3);
                }
            }
        }
    }
}

// qa_out batched over blockIdx.z; FUSED RMS-norm (qn_w), no RoPE.
__global__ void __launch_bounds__(256) gemm_qaout_kernel(
    const ushort_t* __restrict__ qah,
    const ushort_t* __restrict__ W, const void* __restrict__ bias,
    const void* __restrict__ qnw,
    ushort_t* __restrict__ qbuf, const int* __restrict__ dflag)
{
    __shared__ ushort_t As[4096], Bs[4096];
    int isf32 = *dflag;
    int m0 = blockIdx.x * 128, n0 = blockIdx.y * 128;
    int z = blockIdx.z;
    const ushort_t* A = qah + (size_t)z * 256;
    f32x4 acc[4][4];
    #pragma unroll
    for (int i = 0; i < 4; i++)
        #pragma unroll
        for (int j = 0; j < 4; j++) acc[i][j] = (f32x4){0.f, 0.f, 0.f, 0.f};
    gemm_mainloop(A, 768, W, 256, m0, n0, 0, 256, As, Bs, acc);
    int tid = threadIdx.x, w = tid >> 6, ln = tid & 63;
    int fr = ln & 15, q = ln >> 4, wm = w & 1, wn = w >> 1;
    float bb[4], nw[4];
    #pragma unroll
    for (int ni = 0; ni < 4; ni++) {
        bb[ni] = ld1(bias, n0 + wn * 64 + ni * 16 + fr, isf32);
        nw[ni] = ld1(qnw, ni * 16 + fr, isf32);
    }
    #pragma unroll
    for (int mi = 0; mi < 4; mi++) {
        #pragma unroll
        for (int e = 0; e < 4; e++) {
            int row = m0 + wm * 64 + mi * 16 + q * 4 + e;
            float v0 = acc[mi][0][e] + bb[0];
            float v1 = acc[mi][1][e] + bb[1];
            float v2 = acc[mi][2][e] + bb[2];
            float v3 = acc[mi][3][e] + bb[3];
            float ss = v0*v0 + v1*v1 + v2*v2 + v3*v3;
            ss += __shfl_xor(ss, 1, 64);
            ss += __shfl_xor(ss, 2, 64);
            ss += __shfl_xor(ss, 4, 64);
            ss += __shfl_xor(ss, 8, 64);
            float inv = rsqrtf(ss * (1.f / 64.f) + 1e-6f);
            int c0 = n0 + wn * 64 + fr;
            store_q(qbuf, row, c0,      1 + z, v0 * inv * nw[0]);
            store_q(qbuf, row, c0 + 16, 1 + z, v1 * inv * nw[1]);
            store_q(qbuf, row, c0 + 32, 1 + z, v2 * inv * nw[2]);
            store_q(qbuf, row, c0 + 48, 1 + z, v3 * inv * nw[3]);
        }
    }
}

// Plain GEMM. EPI 0: f32 out, split-K partials via blockIdx.z -> o0..o3
// (bias only at z=0). EPI 2: gelu -> bf16 row-major to o0.
template <int EPI>
__global__ void __launch_bounds__(256) gemm_plain_kernel(
    const ushort_t* __restrict__ A, int lda,
    const ushort_t* __restrict__ W, int ldw,
    const void* __restrict__ bias,
    void* __restrict__ o0, void* __restrict__ o1,
    void* __restrict__ o2, void* __restrict__ o3,
    int ldc, int ksub, const int* __restrict__ dflag)
{
    __shared__ ushort_t As[4096], Bs[4096];
    int isf32 = *dflag;
    int m0 = blockIdx.x * 128, n0 = blockIdx.y * 128;
    int z = blockIdx.z;
    void* Cout = (z == 0) ? o0 : (z == 1) ? o1 : (z == 2) ? o2 : o3;
    f32x4 acc[4][4];
    #pragma unroll
    for (int i = 0; i < 4; i++)
        #pragma unroll
        for (int j = 0; j < 4; j++) acc[i][j] = (f32x4){0.f, 0.f, 0.f, 0.f};
    gemm_mainloop(A, lda, W, ldw, m0, n0, z * ksub, ksub, As, Bs, acc);
    int tid = threadIdx.x, w = tid >> 6, ln = tid & 63;
    int fr = ln & 15, q = ln >> 4, wm = w & 1, wn = w >> 1;
    #pragma unroll
    for (int ni = 0; ni < 4; ni++) {
        int c = n0 + wn * 64 + ni * 16 + fr;
        float bb = (z == 0) ? ld1(bias, c, isf32) : 0.f;
        #pragma unroll
        for (int mi = 0; mi < 4; mi++) {
            #pragma unroll
            for (int e = 0; e < 4; e++) {
                int row = m0 + wm * 64 + mi * 16 + q * 4 + e;
                float v = acc[mi][ni][e] + bb;
                if (EPI == 2) {
                    ((ushort_t*)Cout)[(size_t)row * ldc + c] = f2bf(gelu_exact(v));
                } else {
                    ((float*)Cout)[(size_t)row * ldc + c] = v;
                }
            }
        }
    }
}

__global__ void __launch_bounds__(256) qrope_ip_kernel(
    ushort_t* __restrict__ qbuf, const void* __restrict__ qnw,
    const int* __restrict__ dflag) {
    int isf32 = *dflag;
    int w = threadIdx.x >> 6, ln = threadIdx.x & 63;
    int flat = blockIdx.x * 4 + w;
    int t = flat & 511, s = (flat >> 9) & 3;
    ushort_t* p = qbuf + (size_t)flat * 64;
    float x = bf2f(p[ln]);
    float ssum = x * x;
    #pragma unroll
    for (int off = 1; off < 64; off <<= 1) ssum += __shfl_xor(ssum, off, 64);
    float y = x * rsqrtf(ssum * (1.f / 64.f) + 1e-6f) * ld1(qnw, ln, isf32);
    if (s == 0) {
        float ang = (float)t * __expf(-(float)(ln & 31) * (9.210340371976184f / 32.f));
        float cs, sn;
        sincosf(ang, &sn, &cs);
        float other = __shfl_xor(y, 32, 64);
        y = y * cs + ((ln < 32) ? -other : other) * sn;
    }
    p[ln] = f2bf(y);
}

__global__ void __launch_bounds__(256) krope_ip_kernel(
    ushort_t* __restrict__ kbuf, const void* __restrict__ knw,
    const int* __restrict__ dflag) {
    int isf32 = *dflag;
    int w = threadIdx.x >> 6, ln = threadIdx.x & 63;
    int flat = blockIdx.x * 4 + w;
    int j = flat % 1792;
    int t = j & 511;
    ushort_t* p = kbuf + (size_t)flat * 64;
    float x = bf2f(p[ln]);
    float ssum = x * x;
    #pragma unroll
    for (int off = 1; off < 64; off <<= 1) ssum += __shfl_xor(ssum, off, 64);
    float y = x * rsqrtf(ssum * (1.f / 64.f) + 1e-6f) * ld1(knw, ln, isf32);
    float ang = (float)t * __expf(-(float)(ln & 31) * (9.210340371976184f / 32.f));
    float cs, sn;
    sincosf(ang, &sn, &cs);
    float other = __shfl_xor(y, 32, 64);
    y = y * cs + ((ln < 32) ? -other : other) * sn;
    p[ln] = f2bf(y);
}

// ---------------------------------------------------------------------------
// MFMA flash attention. Single-buffered K/V LDS (27.6 KB -> 5 blocks/CU),
// register prefetch, 2 barriers/tile, XCD-aware 1D swizzle.
// ---------------------------------------------------------------------------
__global__ void __launch_bounds__(256) attn_mfma_kernel(
    const ushort_t* __restrict__ qbuf, const ushort_t* __restrict__ kbuf,
    const ushort_t* __restrict__ vbufT, const float* __restrict__ consts,
    float* __restrict__ pacc0, float* __restrict__ pacc1,
    float* __restrict__ pml) {
    __shared__ ushort_t ks[64][72];
    __shared__ ushort_t vsT[64][72];
    __shared__ ushort_t ps[4][16][72];
    int id = blockIdx.x;
    int g  = (id & 7) | ((id >> 6) << 3);      // 0..127
    int qx = (id >> 3) & 7;
    int bh = g & 63;
    int z  = g >> 6;
    int tid = threadIdx.x, w = tid >> 6, ln = tid & 63;
    int r0 = qx * 64 + w * 16;
    int m = ln & 15, quad = ln >> 4;
    const int ntile = z ? 12 : 16;     // 8+8 or 8+4 64-key tiles
    const int keybase = z * 1024;
    const int s0i = z * 2;

    const ushort_t* qb = qbuf + (size_t)bh * 4 * 512 * 64;
    bf16x8 qA0f = *(const bf16x8*)(qb + ((size_t)(s0i * 512 + r0 + m)) * 64 + quad * 8);
    bf16x8 qA1f = *(const bf16x8*)(qb + ((size_t)(s0i * 512 + r0 + m)) * 64 + 32 + quad * 8);
    bf16x8 qB0f = *(const bf16x8*)(qb + ((size_t)((s0i + 1) * 512 + r0 + m)) * 64 + quad * 8);
    bf16x8 qB1f = *(const bf16x8*)(qb + ((size_t)((s0i + 1) * 512 + r0 + m)) * 64 + 32 + quad * 8);

    const float aA = consts[s0i],     bA = consts[4 + s0i];
    const float aB = consts[s0i + 1], bB = consts[4 + s0i + 1];

    float m_i[4], l_i[4];
    f32x4 acc[4];
    #pragma unroll
    for (int e = 0; e < 4; e++) { m_i[e] = -1e30f; l_i[e] = 0.f; }
    #pragma unroll
    for (int d = 0; d < 4; d++) acc[d] = (f32x4){0.f, 0.f, 0.f, 0.f};

    const ushort_t* kb  = kbuf  + (size_t)bh * 1792 * 64 + (size_t)keybase * 64;
    const ushort_t* vbT = vbufT + (size_t)bh * 64 * 1792 + keybase;
    int skey = tid >> 3, sd = (tid & 7) * 8;
    uint4 kreg0 = *(const uint4*)(kb + (size_t)skey * 64 + sd);
    uint4 kreg1 = *(const uint4*)(kb + (size_t)(skey + 32) * 64 + sd);
    uint4 vreg0 = *(const uint4*)(vbT + (size_t)skey * 1792 + sd);
    uint4 vreg1 = *(const uint4*)(vbT + (size_t)(skey + 32) * 1792 + sd);
    *(uint4*)&ks[skey][sd]       = kreg0;
    *(uint4*)&ks[skey + 32][sd]  = kreg1;
    *(uint4*)&vsT[skey][sd]      = vreg0;
    *(uint4*)&vsT[skey + 32][sd] = vreg1;
    __syncthreads();

    for (int ti = 0; ti < ntile; ti++) {
        const bool pf = (ti + 1 < ntile);
        if (pf) {                      // prefetch next 64-key tile into regs
            int nx = (ti + 1) * 64;
            kreg0 = *(const uint4*)(kb + (size_t)(nx + skey) * 64 + sd);
            kreg1 = *(const uint4*)(kb + (size_t)(nx + skey + 32) * 64 + sd);
            vreg0 = *(const uint4*)(vbT + (size_t)skey * 1792 + nx + sd);
            vreg1 = *(const uint4*)(vbT + (size_t)(skey + 32) * 1792 + nx + sd);
        }
        int sl = (ti >= 8) ? 1 : 0;
        float a_s = sl ? aB : aA;
        float b_s = sl ? bB : bA;
        bf16x8 qA0 = sl ? qB0f : qA0f;
        bf16x8 qA1 = sl ? qB1f : qA1f;
        // QK^T: S[16q x 64key] as four C-frags
        f32x4 zero = {0.f, 0.f, 0.f, 0.f};
        bf16x8 k0a = *(const bf16x8*)&ks[m][quad * 8];
        bf16x8 k0b = *(const bf16x8*)&ks[m][32 + quad * 8];
        bf16x8 k1a = *(const bf16x8*)&ks[16 + m][quad * 8];
        bf16x8 k1b = *(const bf16x8*)&ks[16 + m][32 + quad * 8];
        bf16x8 k2a = *(const bf16x8*)&ks[32 + m][quad * 8];
        bf16x8 k2b = *(const bf16x8*)&ks[32 + m][32 + quad * 8];
        bf16x8 k3a = *(const bf16x8*)&ks[48 + m][quad * 8];
        bf16x8 k3b = *(const bf16x8*)&ks[48 + m][32 + quad * 8];
        f32x4 sc0 = __builtin_amdgcn_mfma_f32_16x16x32_bf16(qA0, k0a, zero, 0, 0, 0);
        sc0 = __builtin_amdgcn_mfma_f32_16x16x32_bf16(qA1, k0b, sc0, 0, 0, 0);
        f32x4 sc1 = __builtin_amdgcn_mfma_f32_16x16x32_bf16(qA0, k1a, zero, 0, 0, 0);
        sc1 = __builtin_amdgcn_mfma_f32_16x16x32_bf16(qA1, k1b, sc1, 0, 0, 0);
        f32x4 sc2 = __builtin_amdgcn_mfma_f32_16x16x32_bf16(qA0, k2a, zero, 0, 0, 0);
        sc2 = __builtin_amdgcn_mfma_f32_16x16x32_bf16(qA1, k2b, sc2, 0, 0, 0);
        f32x4 sc3 = __builtin_amdgcn_mfma_f32_16x16x32_bf16(qA0, k3a, zero, 0, 0, 0);
        sc3 = __builtin_amdgcn_mfma_f32_16x16x32_bf16(qA1, k3b, sc3, 0, 0, 0);
        // online softmax per row: max reduce across 16 m-lanes; l kept as
        // per-lane partial; rescale only when running max grows > 8 (T13).
        #pragma unroll
        for (int e = 0; e < 4; e++) {
            float s0 = sc0[e] * a_s + b_s;
            float s1 = sc1[e] * a_s + b_s;
            float s2 = sc2[e] * a_s + b_s;
            float s3 = sc3[e] * a_s + b_s;
            float mxe = fmaxf(fmaxf(s0, s1), fmaxf(s2, s3));
            #pragma unroll
            for (int off = 1; off < 16; off <<= 1) mxe = fmaxf(mxe, __shfl_xor(mxe, off, 64));
            if (mxe > m_i[e] + 8.f) {
                float alpha = __expf(m_i[e] - mxe);
                m_i[e] = mxe;
                l_i[e] *= alpha;
                acc[0][e] *= alpha; acc[1][e] *= alpha;
                acc[2][e] *= alpha; acc[3][e] *= alpha;
            }
            float p0 = __expf(s0 - m_i[e]), p1 = __expf(s1 - m_i[e]);
            float p2 = __expf(s2 - m_i[e]), p3 = __expf(s3 - m_i[e]);
            l_i[e] += (p0 + p1) + (p2 + p3);
            int row = quad * 4 + e;
            ps[w][row][m]      = f2bf(p0);
            ps[w][row][m + 16] = f2bf(p1);
            ps[w][row][m + 32] = f2bf(p2);
            ps[w][row][m + 48] = f2bf(p3);
        }
        // PV: per-wave ps, intra-wave lgkmcnt ordering suffices
        bf16x8 pA0 = *(const bf16x8*)&ps[w][m][quad * 8];
        bf16x8 pA1 = *(const bf16x8*)&ps[w][m][32 + quad * 8];
        #pragma unroll
        for (int dsub = 0; dsub < 4; dsub++) {
            bf16x8 vB0 = *(const bf16x8*)&vsT[dsub * 16 + m][quad * 8];
            bf16x8 vB1 = *(const bf16x8*)&vsT[dsub * 16 + m][32 + quad * 8];
            acc[dsub] = __builtin_amdgcn_mfma_f32_16x16x32_bf16(pA0, vB0, acc[dsub], 0, 0, 0);
            acc[dsub] = __builtin_amdgcn_mfma_f32_16x16x32_bf16(pA1, vB1, acc[dsub], 0, 0, 0);
        }
        if (pf) {
            __syncthreads();           // all waves done reading ks/vsT
            *(uint4*)&ks[skey][sd]       = kreg0;
            *(uint4*)&ks[skey + 32][sd]  = kreg1;
            *(uint4*)&vsT[skey][sd]      = vreg0;
            *(uint4*)&vsT[skey + 32][sd] = vreg1;
            __syncthreads();           // next tile visible
        }
    }
    // reduce per-lane l partials across the 16 m-lanes of each row
    #pragma unroll
    for (int e = 0; e < 4; e++) {
        float l = l_i[e];
        #pragma unroll
        for (int off = 1; off < 16; off <<= 1) l += __shfl_xor(l, off, 64);
        l_i[e] = l;
    }
    float* pacc = z ? pacc1 : pacc0;
    #pragma unroll
    for (int e = 0; e < 4; e++) {
        int t = r0 + quad * 4 + e;
        if (m == 0) {
            size_t mi = (((size_t)z * 64 + bh) * 512 + t) * 2;
            pml[mi]     = m_i[e];
            pml[mi + 1] = l_i[e];
        }
        #pragma unroll
        for (int dsub = 0; dsub < 4; dsub++) {
            pacc[((size_t)bh * 512 + t) * 64 + dsub * 16 + m] = acc[dsub][e];
        }
    }
}

__global__ void __launch_bounds__(256) attn_combine_kernel(
    const float* __restrict__ pacc0, const float* __restrict__ pacc1,
    const float* __restrict__ pml, ushort_t* __restrict__ attn_out) {
    int tid = threadIdx.x, w = tid >> 6, ln = tid & 63;
    int idx = blockIdx.x * 4 + w;           // 0..32767 = bh*512 + t
    int bh = idx >> 9, t = idx & 511;
    int b = bh >> 4, h = bh & 15;
    size_t r = (size_t)bh * 512 + t;
    float m0 = pml[r * 2],                 l0 = pml[r * 2 + 1];
    float m1 = pml[((size_t)32768 + r) * 2], l1 = pml[((size_t)32768 + r) * 2 + 1];
    float M = fmaxf(m0, m1);
    float w0 = __expf(m0 - M), w1 = __expf(m1 - M);
    float inv = 1.f / (l0 * w0 + l1 * w1);
    float a0 = pacc0[r * 64 + ln];
    float a1 = pacc1[r * 64 + ln];
    attn_out[(((size_t)(b * 512 + t)) * 16 + h) * 64 + ln] = f2bf((a0 * w0 + a1 * w1) * inv);
}

// ---------------------------------------------------------------------------
// Legacy full-key attention (fallback path only).
// ---------------------------------------------------------------------------
__global__ void __launch_bounds__(256) attn_mfma_legacy_kernel(
    const ushort_t* __restrict__ qbuf, const ushort_t* __restrict__ kbuf,
    const ushort_t* __restrict__ vbufT, const float* __restrict__ consts,
    ushort_t* __restrict__ attn_out) {
    __shared__ ushort_t ks[2][64][72];
    __shared__ ushort_t vsT[2][64][72];
    __shared__ ushort_t ps[4][16][72];
    int bh = blockIdx.y;
    int b = bh >> 4, h = bh & 15;
    int tid = threadIdx.x, w = tid >> 6, ln = tid & 63;
    int r0 = blockIdx.x * 64 + w * 16;
    int m = ln & 15, quad = ln >> 4;
    const ushort_t* qb = qbuf + (size_t)bh * 4 * 512 * 64;
    bf16x8 qf[4][2];
    #pragma unroll
    for (int s = 0; s < 4; s++) {
        qf[s][0] = *(const bf16x8*)(qb + ((size_t)(s * 512 + r0 + m)) * 64 + quad * 8);
        qf[s][1] = *(const bf16x8*)(qb + ((size_t)(s * 512 + r0 + m)) * 64 + 32 + quad * 8);
    }
    float m_i[4], l_i[4];
    f32x4 acc[4];
    #pragma unroll
    for (int e = 0; e < 4; e++) { m_i[e] = -1e30f; l_i[e] = 0.f; }
    #pragma unroll
    for (int d = 0; d < 4; d++) acc[d] = (f32x4){0.f, 0.f, 0.f, 0.f};
    const ushort_t* kb  = kbuf  + (size_t)bh * 1792 * 64;
    const ushort_t* vbT = vbufT + (size_t)bh * 64 * 1792;
    int skey = tid >> 3, sd = (tid & 7) * 8;
    uint4 kreg0 = *(const uint4*)(kb + (size_t)skey * 64 + sd);
    uint4 kreg1 = *(const uint4*)(kb + (size_t)(skey + 32) * 64 + sd);
    uint4 vreg0 = *(const uint4*)(vbT + (size_t)skey * 1792 + sd);
    uint4 vreg1 = *(const uint4*)(vbT + (size_t)(skey + 32) * 1792 + sd);
    *(uint4*)&ks[0][skey][sd]       = kreg0;
    *(uint4*)&ks[0][skey + 32][sd]  = kreg1;
    *(uint4*)&vsT[0][skey][sd]      = vreg0;
    *(uint4*)&vsT[0][skey + 32][sd] = vreg1;
    __syncthreads();
    int tcnt = 0, p = 0;
    #pragma unroll
    for (int s = 0; s < 4; s++) {
        const float a_s = consts[s];
        const float b_s = consts[4 + s];
        const bf16x8 qA0 = qf[s][0];
        const bf16x8 qA1 = qf[s][1];
        const int NT = (s == 3) ? 4 : 8;
        for (int ti = 0; ti < NT; ti++) {
            if (tcnt < 27) {
                int nx = (tcnt + 1) * 64;
                kreg0 = *(const uint4*)(kb + (size_t)(nx + skey) * 64 + sd);
                kreg1 = *(const uint4*)(kb + (size_t)(nx + skey + 32) * 64 + sd);
                vreg0 = *(const uint4*)(vbT + (size_t)skey * 1792 + nx + sd);
                vreg1 = *(const uint4*)(vbT + (size_t)(skey + 32) * 1792 + nx + sd);
            }
            f32x4 zero = {0.f, 0.f, 0.f, 0.f};
            bf16x8 k0a = *(const bf16x8*)&ks[p][m][quad * 8];
            bf16x8 k0b = *(const bf16x8*)&ks[p][m][32 + quad * 8];
            bf16x8 k1a = *(const bf16x8*)&ks[p][16 + m][quad * 8];
            bf16x8 k1b = *(const bf16x8*)&ks[p][16 + m][32 + quad * 8];
            bf16x8 k2a = *(const bf16x8*)&ks[p][32 + m][quad * 8];
            bf16x8 k2b = *(const bf16x8*)&ks[p][32 + m][32 + quad * 8];
            bf16x8 k3a = *(const bf16x8*)&ks[p][48 + m][quad * 8];
            bf16x8 k3b = *(const bf16x8*)&ks[p][48 + m][32 + quad * 8];
            f32x4 sc0 = __builtin_amdgcn_mfma_f32_16x16x32_bf16(qA0, k0a, zero, 0, 0, 0);
            sc0 = __builtin_amdgcn_mfma_f32_16x16x32_bf16(qA1, k0b, sc0, 0, 0, 0);
            f32x4 sc1 = __builtin_amdgcn_mfma_f32_16x16x32_bf16(qA0, k1a, zero, 0, 0, 0);
            sc1 = __builtin_amdgcn_mfma_f32_16x16x32_bf16(qA1, k1b, sc1, 0, 0, 0);
            f32x4 sc2 = __builtin_amdgcn_mfma_f32_16x16x32_bf16(qA0, k2a, zero, 0, 0, 0);
            sc2 = __builtin_amdgcn_mfma_f32_16x16x32_bf16(qA1, k2b, sc2, 0, 0, 0);
            f32x4 sc3 = __builtin_amdgcn_mfma_f32_16x16x32_bf16(qA0, k3a, zero, 0, 0, 0);
            sc3 = __builtin_amdgcn_mfma_f32_16x16x32_bf16(qA1, k3b, sc3, 0, 0, 0);
            #pragma unroll
            for (int e = 0; e < 4; e++) {
                float s0 = sc0[e] * a_s + b_s;
                float s1 = sc1[e] * a_s + b_s;
                float s2 = sc2[e] * a_s + b_s;
                float s3 = sc3[e] * a_s + b_s;
                float mxe = fmaxf(fmaxf(s0, s1), fmaxf(s2, s3));
                #pragma unroll
                for (int off = 1; off < 16; off <<= 1) mxe = fmaxf(mxe, __shfl_xor(mxe, off, 64));
                if (mxe > m_i[e] + 8.f) {
                    float alpha = __expf(m_i[e] - mxe);
                    m_i[e] = mxe;
                    l_i[e] *= alpha;
                    acc[0][e] *= alpha; acc[1][e] *= alpha;
                    acc[2][e] *= alpha; acc[3][e] *= alpha;
                }
                float p0 = __expf(s0 - m_i[e]), p1 = __expf(s1 - m_i[e]);
                float p2 = __expf(s2 - m_i[e]), p3 = __expf(s3 - m_i[e]);
                l_i[e] += (p0 + p1) + (p2 + p3);
                int row = quad * 4 + e;
                ps[w][row][m]      = f2bf(p0);
                ps[w][row][m + 16] = f2bf(p1);
                ps[w][row][m + 32] = f2bf(p2);
                ps[w][row][m + 48] = f2bf(p3);
            }
            bf16x8 pA0 = *(const bf16x8*)&ps[w][m][quad * 8];
            bf16x8 pA1 = *(const bf16x8*)&ps[w][m][32 + quad * 8];
            #pragma unroll
            for (int dsub = 0; dsub < 4; dsub++) {
                bf16x8 vB0 = *(const bf16x8*)&vsT[p][dsub * 16 + m][quad * 8];
                bf16x8 vB1 = *(const bf16x8*)&vsT[p][dsub * 16 + m][32 + quad * 8];
                acc[dsub] = __builtin_amdgcn_mfma_f32_16x16x32_bf16(pA0, vB0, acc[dsub], 0, 0, 0);
                acc[dsub] = __builtin_amdgcn_mfma_f32_16x16x32_bf16(pA1, vB1, acc[dsub], 0, 0, 0);
            }
            if (tcnt < 27) {
                *(uint4*)&ks[1 - p][skey][sd]       = kreg0;
                *(uint4*)&ks[1 - p][skey + 32][sd]  = kreg1;
                *(uint4*)&vsT[1 - p][skey][sd]      = vreg0;
                *(uint4*)&vsT[1 - p][skey + 32][sd] = vreg1;
            }
            __syncthreads();
            p ^= 1;
            tcnt++;
        }
    }
    #pragma unroll
    for (int e = 0; e < 4; e++) {
        float l = l_i[e];
        #pragma unroll
        for (int off = 1; off < 16; off <<= 1) l += __shfl_xor(l, off, 64);
        float invl = 1.f / l;
        int t = r0 + quad * 4 + e;
        #pragma unroll
        for (int dsub = 0; dsub < 4; dsub++) {
            int d = dsub * 16 + m;
            attn_out[(((size_t)(b * 512 + t)) * 16 + h) * 64 + d] = f2bf(acc[dsub][e] * invl);
        }
    }
}

__global__ void resgate_kernel(const void* __restrict__ x, const float* __restrict__ p0,
                               const float* __restrict__ p1, const float* __restrict__ p2,
                               const float* __restrict__ p3,
                               const float* __restrict__ mod, float* __restrict__ x1,
                               int sum4, const int* __restrict__ dflag) {
    int isf32 = *dflag;
    int i = blockIdx.x * 256 + threadIdx.x;
    int b = i >> 19, n = i & 1023;
    float proj = p0[i];
    if (sum4) proj += p1[i] + p2[i] + p3[i];
    x1[i] = ld1(x, i, isf32) + mod[(size_t)b * 6144 + 2048 + n] * proj;
}
__global__ void final_kernel(const float* __restrict__ x1, const float* __restrict__ f0,
                             const float* __restrict__ f1, const float* __restrict__ f2,
                             const float* __restrict__ f3,
                             const float* __restrict__ mod, void* __restrict__ out,
                             int sum4, const int* __restrict__ dflag) {
    int isf32 = *dflag;
    int i = blockIdx.x * 256 + threadIdx.x;
    int b = i >> 19, n = i & 1023;
    float ffn = f0[i];
    if (sum4) ffn += f1[i] + f2[i] + f3[i];
    float val = x1[i] + mod[(size_t)b * 6144 + 5120 + n] * ffn;
    if (isf32) ((float*)out)[i] = val;
    else       ((ushort_t*)out)[i] = f2bf(val);
}

static constexpr size_t OFF_CONSTS   = 0;
static constexpr size_t OFF_FLAG     = 64;
static constexpr size_t OFF_MOD      = 512;
static constexpr size_t OFF_XNORM    = OFF_MOD    + 98304;      // 98816
static constexpr size_t OFF_QAH      = OFF_XNORM  + 4194304;
static constexpr size_t OFF_KBUF     = OFF_XNORM  + 8388608;    // 8487424
static constexpr size_t OFF_VBUF     = OFF_KBUF   + 14680064;   // 23167488
static constexpr size_t OFF_QBUF     = OFF_VBUF   + 14680064;   // 37847552
static constexpr size_t OFF_ATTNOUT  = OFF_QBUF   + 16777216;   // 54624768
static constexpr size_t OFF_WCACHE   = OFF_ATTNOUT + 4194304;   // 58819072
static constexpr size_t OFF_PACC1    = OFF_WCACHE + CW_TOTAL * 2;   // 98664960
static constexpr size_t OFF_PML      = OFF_PACC1  + 8388608;        // 107053568
static constexpr size_t OFF_ROPE     = OFF_PML    + 524288;         // 107577856 (+131072)
static constexpr size_t WS_NEED      = OFF_WCACHE + 52428800;   // unchanged, known-good

extern "C" void kernel_launch(void* const* d_in, const int* in_sizes, int n_in,
                              void* d_out, int out_size, void* d_ws, size_t ws_size,
                              hipStream_t stream) {
    (void)in_sizes; (void)n_in; (void)out_size;
    const void* x        = d_in[0];
    const void* bev      = d_in[1];
    const void* vl       = d_in[2];
    const void* reas     = d_in[3];
    const void* cond     = d_in[4];
    const void* ln_pre_w = d_in[5];
    const void* ln_pre_b = d_in[6];
    const void* adaln_w  = d_in[7];
    const void* adaln_b  = d_in[8];
    const void* q_proj_w = d_in[9];
    const void* q_proj_b = d_in[10];
    const void* qa_w     = d_in[11];
    const void* qa_b     = d_in[12];
    const void* qa_out_w = d_in[13];
    const void* qa_out_b = d_in[14];
    const void* k_w      = d_in[15];
    const void* k_b      = d_in[16];
    const void* v_w      = d_in[17];
    const void* v_b      = d_in[18];
    const void* o_w      = d_in[19];
    const void* o_b      = d_in[20];
    const void* qn_w     = d_in[21];
    const void* kn_w     = d_in[22];
    const void* gating   = d_in[23];
    const void* temps    = d_in[24];
    const void* sbias    = d_in[25];
    const void* ffn_ln_w = d_in[26];
    const void* ffn_ln_b = d_in[27];
    const void* ffn_w1   = d_in[28];
    const void* ffn_b1   = d_in[29];
    const void* ffn_w2   = d_in[30];
    const void* ffn_b2   = d_in[31];

    char* ws = (char*)d_ws;
    float*    consts   = (float*)(ws + OFF_CONSTS);
    int*      dflag    = (int*)(ws + OFF_FLAG);
    float*    mod      = (float*)(ws + OFF_MOD);
    ushort_t* xnorm    = (ushort_t*)(ws + OFF_XNORM);
    ushort_t* qah      = (ushort_t*)(ws + OFF_QAH);
    ushort_t* kbuf     = (ushort_t*)(ws + OFF_KBUF);
    ushort_t* vbufT    = (ushort_t*)(ws + OFF_VBUF);
    ushort_t* qbuf     = (ushort_t*)(ws + OFF_QBUF);
    ushort_t* attnout  = (ushort_t*)(ws + OFF_ATTNOUT);
    float*    x1       = (float*)(ws + OFF_XNORM);
    ushort_t* hmid     = (ushort_t*)(ws + OFF_KBUF);
    ushort_t* hin      = (ushort_t*)(ws + OFF_ATTNOUT);
    ushort_t* wc       = (ushort_t*)(ws + OFF_WCACHE);
    float*    ropetab  = (float*)(ws + OFF_ROPE);
    // attention partials / staged activations
    float*    pacc0    = (float*)(ws + OFF_XNORM);               // xnorm+qah dead by attn
    float*    pacc1    = (float*)(ws + OFF_PACC1);
    float*    pml      = (float*)(ws + OFF_PML);
    ushort_t* actA     = (ushort_t*)(ws + OFF_PACC1);            // bev+vl bf16 (pre-attn)
    ushort_t* actB     = (ushort_t*)(ws + OFF_ATTNOUT);          // reas bf16 (pre-attn)
    // o-proj split-K partials (kbuf/vbuf/qbuf dead after attention)
    float*    op0      = (float*)(ws + OFF_KBUF);
    float*    op1      = (float*)(ws + OFF_KBUF + 8388608);
    float*    op2      = (float*)(ws + OFF_KBUF + 16777216);
    float*    op3      = (float*)(ws + OFF_QBUF);
    // ffn2 split-K partials (hmid occupies OFF_KBUF..+16M, keep clear of it)
    float*    f0       = (float*)(ws + OFF_QBUF);
    float*    f1       = (float*)(ws + OFF_QBUF + 8388608);
    float*    f2       = (float*)(ws + OFF_KBUF + 16777216);
    float*    f3       = (float*)(ws + OFF_PACC1);

    const bool use_cache = (ws_size >= WS_NEED);

    detect_kernel<<<1, 64, 0, stream>>>((const unsigned int*)x, dflag);
    prep_consts_kernel<<<1, 64, 0, stream>>>(temps, sbias, gating, consts, dflag);

    if (use_cache) {
        prep_rope_kernel<<<64, 256, 0, stream>>>(ropetab);
        convert_weights_kernel<<<9728, 256, 0, stream>>>(
            q_proj_w, qa_w, qa_out_w, k_w, v_w, o_w, ffn_w1, ffn_w2, wc, dflag);
        convert_act3_kernel<<<2560, 256, 0, stream>>>(bev, vl, reas, actA, actB, dflag);
        adaln_init_kernel<<<24, 256, 0, stream>>>(adaln_b, mod, dflag);
        adaln_kernel<<<dim3(24, 4, 4), 256, 0, stream>>>(cond, adaln_w, mod, dflag);
        ln_mod_kernel<0><<<2048, 256, 0, stream>>>(x, mod, ln_pre_w, ln_pre_b, 0, 1024, xnorm, dflag);

        // Merged stage-1 with fused RMS+RoPE epilogues (1120 blocks)
        gemm_stage1_kernel<<<1120, 256, 0, stream>>>(
            xnorm, actA, actB,
            wc + CW_QPROJ, wc + CW_QA, wc + CW_KW, wc + CW_VW,
            q_proj_b, qa_b, k_b, v_b, qn_w, kn_w, ropetab,
            qbuf, qah, kbuf, vbufT, dflag);
        // qa_out x3 with fused RMS (qn_w), no rope (adapters)
        gemm_qaout_kernel<<<dim3(16, 8, 3), 256, 0, stream>>>(
            qah, wc + CW_QAOUT, qa_out_b, qn_w, qbuf, dflag);

        attn_mfma_kernel<<<1024, 256, 0, stream>>>(
            qbuf, kbuf, vbufT, consts, pacc0, pacc1, pml);
        attn_combine_kernel<<<8192, 256, 0, stream>>>(pacc0, pacc1, pml, attnout);

        // o-proj split-K=4 (512 blocks)
        gemm_plain_kernel<0><<<dim3(16, 8, 4), 256, 0, stream>>>(
            attnout, 1024, wc + CW_OW, 1024, o_b, op0, op1, op2, op3, 1024, 256, dflag);
        // fused residual-gate + FFN LayerNorm (writes x1 f32 + hin bf16)
        resgate_ln_kernel<<<2048, 256, 0, stream>>>(
            x, op0, op1, op2, op3, mod, ffn_ln_w, ffn_ln_b, x1, hin, dflag);
        gemm_plain_kernel<2><<<dim3(16, 32, 1), 256, 0, stream>>>(
            hin, 1024, wc + CW_FFN1, 1024, ffn_b1, hmid, nullptr, nullptr, nullptr, 4096, 1024, dflag);
        // ffn2 split-K=4 (512 blocks)
        gemm_plain_kernel<0><<<dim3(16, 8, 4), 256, 0, stream>>>(
            hmid, 4096, wc + CW_FFN2, 4096, ffn_b2, f0, f1, f2, f3, 1024, 1024, dflag);
        final_kernel<<<8192, 256, 0, stream>>>(x1, f0, f1, f2, f3, mod, d_out, 1, dflag);
    } else {
        // Fallback: legacy 64x64 path reading original weights directly.
        float* proj0L = (float*)(ws + OFF_QBUF);
        adaln_init_kernel<<<24, 256, 0, stream>>>(adaln_b, mod, dflag);
        adaln_kernel<<<dim3(24, 4, 4), 256, 0, stream>>>(cond, adaln_w, mod, dflag);
        ln_mod_kernel<0><<<2048, 256, 0, stream>>>(x, mod, ln_pre_w, ln_pre_b, 0, 1024, xnorm, dflag);
        gemm_bt_kernel<4><<<dim3(32, 16), 256, 0, stream>>>(xnorm, 1024, q_proj_w, 0, q_proj_b, qbuf, 0, 1024, 0, 9, 0, 0, dflag);
        {
            const void* srcs[4] = {xnorm, bev, vl, reas};
            const int koffs[4] = {0, 512, 1024, 1536};
            const int p1s[4]   = {9, 9, 9, 8};
            for (int i = 0; i < 4; i++) {
                int aext = (i == 0) ? 0 : 1;
                int gx = (i == 3) ? 16 : 32;
                gemm_bt_kernel<3><<<dim3(gx, 16), 256, 0, stream>>>(
                    srcs[i], 1024, k_w, i * 1024, k_b, kbuf, 0, 1024, koffs[i], p1s[i], aext, 0, dflag);
                gemm_bt_kernel<5><<<dim3(gx, 16), 256, 0, stream>>>(
                    srcs[i], 1024, v_w, i * 1024, v_b, vbufT, 0, 1024, koffs[i], p1s[i], aext, 0, dflag);
            }
        }
        gemm_bt_kernel<1><<<dim3(32, 12), 256, 0, stream>>>(xnorm, 1024, qa_w, 0, qa_b, qah, 768, 1024, 0, 0, 0, 0, dflag);
        for (int i = 0; i < 3; i++)
            gemm_bt_kernel<4><<<dim3(32, 16), 256, 0, stream>>>(qah + i * 256, 768, qa_out_w, 0, qa_out_b,
                                                                qbuf, 0, 256, 1 + i, 9, 0, 0, dflag);
        qrope_ip_kernel<<<32768, 256, 0, stream>>>(qbuf, qn_w, dflag);
        krope_ip_kernel<<<28672, 256, 0, stream>>>(kbuf, kn_w, dflag);
        attn_mfma_legacy_kernel<<<dim3(8, 64), 256, 0, stream>>>(qbuf, kbuf, vbufT, consts, attnout);
        gemm_bt_kernel<0><<<dim3(32, 16), 256, 0, stream>>>(attnout, 1024, o_w, 0, o_b, proj0L, 1024, 1024, 0, 0, 0, 0, dflag);
        resgate_kernel<<<8192, 256, 0, stream>>>(x, proj0L, proj0L, proj0L, proj0L, mod, x1, 0, dflag);
        ln_mod_kernel<1><<<2048, 256, 0, stream>>>(x1, mod, ffn_ln_w, ffn_ln_b, 3072, 4096, hin, dflag);
        gemm_bt_kernel<2><<<dim3(32, 64), 256, 0, stream>>>(hin, 1024, ffn_w1, 0, ffn_b1, hmid, 4096, 1024, 0, 0, 0, 0, dflag);
        gemm_bt_kernel<0><<<dim3(32, 16), 256, 0, stream>>>(hmid, 4096, ffn_w2, 0, ffn_b2, proj0L, 1024, 4096, 0, 0, 0, 0, dflag);
        final_kernel<<<8192, 256, 0, stream>>>(x1, proj0L, proj0L, proj0L, proj0L, mod, d_out, 0, dflag);
    }
}

// Round 10
// 505.427 us; speedup vs baseline: 1.0243x; 1.0243x over previous
//
#include <hip/hip_runtime.h>

typedef unsigned short ushort_t;
typedef __attribute__((ext_vector_type(8))) __bf16 bf16x8;
typedef __attribute__((ext_vector_type(4))) float f32x4;

__device__ __forceinline__ float bf2f(ushort_t u) {
    union { unsigned int i; float f; } v; v.i = ((unsigned int)u) << 16; return v.f;
}
__device__ __forceinline__ ushort_t f2bf(float f) {
    union { float f; unsigned int i; } v; v.f = f;
    unsigned int r = (v.i + 0x7FFFu + ((v.i >> 16) & 1u)) >> 16;
    return (ushort_t)r;
}
__device__ __forceinline__ float gelu_exact(float v) {
    return 0.5f * v * (1.f + erff(v * 0.70710678118654752f));
}
__device__ __forceinline__ float ld1(const void* p, size_t i, int isf32) {
    return isf32 ? ((const float*)p)[i] : bf2f(((const ushort_t*)p)[i]);
}
__device__ __forceinline__ void stage8(const void* p, size_t idx, int isf32, ushort_t* dst) {
    if (isf32) {
        const float* f = (const float*)p + idx;
        float4 u = *(const float4*)f;
        float4 v = *(const float4*)(f + 4);
        dst[0] = f2bf(u.x); dst[1] = f2bf(u.y); dst[2] = f2bf(u.z); dst[3] = f2bf(u.w);
        dst[4] = f2bf(v.x); dst[5] = f2bf(v.y); dst[6] = f2bf(v.z); dst[7] = f2bf(v.w);
    } else {
        *(uint4*)dst = *(const uint4*)((const ushort_t*)p + idx);
    }
}
// async global->LDS, 16B per lane; LDS dest must be wave-uniform base (HW adds lane*16)
__device__ __forceinline__ void gload16(const ushort_t* g, ushort_t* l) {
    __builtin_amdgcn_global_load_lds(
        (const __attribute__((address_space(1))) unsigned int*)g,
        (__attribute__((address_space(3))) unsigned int*)l, 16, 0, 0);
}

// scatter stores into attention-layout buffers
__device__ __forceinline__ void store_q(ushort_t* qbuf, int row, int c, int p0, float v) {
    int b = row >> 9, t = row & 511;
    qbuf[((((size_t)(b * 16 + (c >> 6))) * 4 + p0) * 512 + t) * 64 + (c & 63)] = f2bf(v);
}
__device__ __forceinline__ void store_k(ushort_t* kbuf, int row, int c, int koff, int p1, float v) {
    int b = row >> p1, t = row & ((1 << p1) - 1);
    kbuf[(((size_t)(b * 16 + (c >> 6))) * 1792 + koff + t) * 64 + (c & 63)] = f2bf(v);
}
__device__ __forceinline__ void store_v(ushort_t* vbufT, int row, int c, int koff, int p1, float v) {
    int b = row >> p1, t = row & ((1 << p1) - 1);
    vbufT[(((size_t)(b * 16 + (c >> 6))) * 64 + (c & 63)) * 1792 + koff + t] = f2bf(v);
}

__global__ void detect_kernel(const unsigned int* __restrict__ x, int* __restrict__ flag) {
    if (threadIdx.x == 0 && blockIdx.x == 0) {
        int sane = 0;
        for (int i = 0; i < 256; i++) {
            unsigned int e = (x[i] >> 7) & 0xFFu;
            if (e == 0u || (e >= 100u && e <= 140u)) sane++;
        }
        *flag = (sane >= 200) ? 0 : 1;
    }
}

// precompute RoPE cos/sin table: [t=0..511][d31=0..31] -> (cos, sin) pairs
__global__ void prep_rope_kernel(float* __restrict__ tab) {
    int idx = blockIdx.x * 256 + threadIdx.x;    // 0..16383
    int t = idx >> 5, d = idx & 31;
    float ang = (float)t * __expf(-(float)d * (9.210340371976184f / 32.f));
    float cs, sn;
    sincosf(ang, &sn, &cs);
    tab[idx * 2]     = cs;
    tab[idx * 2 + 1] = sn;
}

// weight cache layout (elements) — adaln NOT cached (read directly by adaln_kernel)
static constexpr size_t CW_QPROJ = 0;          // 1024x1024
static constexpr size_t CW_QA    = 1048576;    // 3x256x1024
static constexpr size_t CW_QAOUT = 1835008;    // 1024x256
static constexpr size_t CW_KW    = 2097152;    // 4x1024x1024
static constexpr size_t CW_VW    = 6291456;    // 4x1024x1024
static constexpr size_t CW_OW    = 10485760;   // 1024x1024
static constexpr size_t CW_FFN1  = 11534336;   // 4096x1024
static constexpr size_t CW_FFN2  = 15728640;   // 1024x4096
static constexpr size_t CW_TOTAL = 19922944;   // elements (x2 bytes = 39.8 MB)

__global__ void __launch_bounds__(256) convert_weights_kernel(
    const void* s0, const void* s1, const void* s2, const void* s3,
    const void* s4, const void* s5, const void* s6, const void* s7,
    ushort_t* __restrict__ dst, const int* __restrict__ dflag) {
    int isf32 = *dflag;
    size_t i8 = ((size_t)blockIdx.x * 256 + threadIdx.x) * 8;
    if (i8 >= CW_TOTAL) return;
    const void* src; size_t base;
    if      (i8 < CW_QA)    { src = s0; base = CW_QPROJ; }
    else if (i8 < CW_QAOUT) { src = s1; base = CW_QA; }
    else if (i8 < CW_KW)    { src = s2; base = CW_QAOUT; }
    else if (i8 < CW_VW)    { src = s3; base = CW_KW; }
    else if (i8 < CW_OW)    { src = s4; base = CW_VW; }
    else if (i8 < CW_FFN1)  { src = s5; base = CW_OW; }
    else if (i8 < CW_FFN2)  { src = s6; base = CW_FFN1; }
    else                    { src = s7; base = CW_FFN2; }
    ushort_t t8[8];
    stage8(src, i8 - base, isf32, t8);
    *(uint4*)(dst + i8) = *(uint4*)t8;
}

// bev(2048 rows) + vl(2048 rows) -> actA; reas(1024 rows) -> actB. All x1024 cols.
__global__ void __launch_bounds__(256) convert_act3_kernel(
    const void* __restrict__ bev, const void* __restrict__ vl,
    const void* __restrict__ reas, ushort_t* __restrict__ actA,
    ushort_t* __restrict__ actB, const int* __restrict__ dflag) {
    int isf32 = *dflag;
    size_t i8 = ((size_t)blockIdx.x * 256 + threadIdx.x) * 8;
    if (i8 >= 5242880) return;
    ushort_t t8[8];
    if (i8 < 2097152) {
        stage8(bev, i8, isf32, t8);
        *(uint4*)(actA + i8) = *(uint4*)t8;
    } else if (i8 < 4194304) {
        stage8(vl, i8 - 2097152, isf32, t8);
        *(uint4*)(actA + i8) = *(uint4*)t8;
    } else {
        stage8(reas, i8 - 4194304, isf32, t8);
        *(uint4*)(actB + (i8 - 4194304)) = *(uint4*)t8;
    }
}

__global__ void prep_consts_kernel(const void* __restrict__ temps,
                                   const void* __restrict__ biases,
                                   const void* __restrict__ gating,
                                   float* __restrict__ consts,
                                   const int* __restrict__ dflag) {
    if (threadIdx.x == 0 && blockIdx.x == 0) {
        int isf32 = *dflag;
        float g = tanhf(ld1(gating, 0, isf32));
        for (int s = 0; s < 4; s++) {
            float t  = ld1(temps, s, isf32);
            float sp = (t > 20.f) ? t : log1pf(expf(t));
            float scale = 0.125f * (1.f + sp);
            float mul = (s == 3) ? g : 1.f;
            consts[s]     = scale * mul;
            consts[4 + s] = ld1(biases, s, isf32) * mul;
        }
    }
}

// mod = bias (broadcast over the 4 batches); adaln_kernel atomically adds partials
__global__ void adaln_init_kernel(const void* __restrict__ bias, float* __restrict__ mod,
                                  const int* __restrict__ dflag) {
    int isf32 = *dflag;
    int n = blockIdx.x * 256 + threadIdx.x;      // 0..6143
    float b = ld1(bias, n, isf32);
    #pragma unroll
    for (int bb = 0; bb < 4; bb++) mod[(size_t)bb * 6144 + n] = b;
}

// grid (24, 4, 4): z splits the 1024-d dot into 4 chunks of 256; partials
// atomicAdd into mod (pre-initialized with bias).
__global__ void __launch_bounds__(256) adaln_kernel(
    const void* __restrict__ cond, const void* __restrict__ w,
    float* __restrict__ mod, const int* __restrict__ dflag) {
    __shared__ float cs[256];
    int isf32 = *dflag;
    int b = blockIdx.y, z = blockIdx.z, tid = threadIdx.x;
    {
        float c = ld1(cond, b * 1024 + z * 256 + tid, isf32);
        cs[tid] = c / (1.f + expf(-c));
    }
    __syncthreads();
    int n = blockIdx.x * 256 + tid;
    float acc = 0.f;
    if (isf32) {
        const float* wr = (const float*)w + (size_t)n * 1024 + z * 256;
        for (int d = 0; d < 256; d += 8) {
            float4 a = *(const float4*)(wr + d);
            float4 bb = *(const float4*)(wr + d + 4);
            acc += cs[d+0]*a.x + cs[d+1]*a.y + cs[d+2]*a.z + cs[d+3]*a.w
                 + cs[d+4]*bb.x + cs[d+5]*bb.y + cs[d+6]*bb.z + cs[d+7]*bb.w;
        }
    } else {
        const ushort_t* wr = (const ushort_t*)w + (size_t)n * 1024 + z * 256;
        for (int d = 0; d < 256; d += 8) {
            uint4 raw = *(const uint4*)(wr + d);
            const ushort_t* u = (const ushort_t*)&raw;
            acc += cs[d+0]*bf2f(u[0]) + cs[d+1]*bf2f(u[1]) + cs[d+2]*bf2f(u[2]) + cs[d+3]*bf2f(u[3])
                 + cs[d+4]*bf2f(u[4]) + cs[d+5]*bf2f(u[5]) + cs[d+6]*bf2f(u[6]) + cs[d+7]*bf2f(u[7]);
        }
    }
    atomicAdd(&mod[(size_t)b * 6144 + n], acc);
}

template <int SRC>
__global__ void __launch_bounds__(256) ln_mod_kernel(
    const void* __restrict__ xin, const float* __restrict__ mod,
    const void* __restrict__ lnw, const void* __restrict__ lnb,
    int shift_off, int scale_off, ushort_t* __restrict__ out,
    const int* __restrict__ dflag) {
    int isf32 = *dflag;
    int row = blockIdx.x, tid = threadIdx.x;
    int b = row >> 9;
    float v[4];
    #pragma unroll
    for (int i = 0; i < 4; i++) {
        size_t idx = (size_t)row * 1024 + tid + 256 * i;
        v[i] = (SRC == 1) ? ((const float*)xin)[idx] : ld1(xin, idx, isf32);
    }
    float s = v[0] + v[1] + v[2] + v[3];
    float ss = v[0]*v[0] + v[1]*v[1] + v[2]*v[2] + v[3]*v[3];
    #pragma unroll
    for (int off = 1; off < 64; off <<= 1) {
        s  += __shfl_xor(s,  off, 64);
        ss += __shfl_xor(ss, off, 64);
    }
    __shared__ float red[8];
    int w = tid >> 6;
    if ((tid & 63) == 0) { red[w] = s; red[4 + w] = ss; }
    __syncthreads();
    s  = red[0] + red[1] + red[2] + red[3];
    ss = red[4] + red[5] + red[6] + red[7];
    float mean = s * (1.f / 1024.f);
    float var  = ss * (1.f / 1024.f) - mean * mean;
    float inv  = rsqrtf(var + 1e-5f);
    const float* mb = mod + (size_t)b * 6144;
    #pragma unroll
    for (int i = 0; i < 4; i++) {
        int d = tid + 256 * i;
        float xn = (v[i] - mean) * inv;
        float y  = xn * ld1(lnw, d, isf32) + ld1(lnb, d, isf32);
        out[(size_t)row * 1024 + d] = f2bf(y * (1.f + mb[scale_off + d]) + mb[shift_off + d]);
    }
}

// Fused residual-gate + FFN LayerNorm: one block per row.
__global__ void __launch_bounds__(256) resgate_ln_kernel(
    const void* __restrict__ x, const float* __restrict__ p0,
    const float* __restrict__ p1, const float* __restrict__ p2,
    const float* __restrict__ p3, const float* __restrict__ mod,
    const void* __restrict__ lnw, const void* __restrict__ lnb,
    float* __restrict__ x1, ushort_t* __restrict__ hin,
    const int* __restrict__ dflag) {
    int isf32 = *dflag;
    int row = blockIdx.x, tid = threadIdx.x;
    int b = row >> 9;
    const float* mb = mod + (size_t)b * 6144;
    float v[4];
    #pragma unroll
    for (int i = 0; i < 4; i++) {
        size_t idx = (size_t)row * 1024 + tid + 256 * i;
        int n = tid + 256 * i;
        float proj = p0[idx] + p1[idx] + p2[idx] + p3[idx];
        v[i] = ld1(x, idx, isf32) + mb[2048 + n] * proj;
        x1[idx] = v[i];
    }
    float s = v[0] + v[1] + v[2] + v[3];
    float ss = v[0]*v[0] + v[1]*v[1] + v[2]*v[2] + v[3]*v[3];
    #pragma unroll
    for (int off = 1; off < 64; off <<= 1) {
        s  += __shfl_xor(s,  off, 64);
        ss += __shfl_xor(ss, off, 64);
    }
    __shared__ float red[8];
    int w = tid >> 6;
    if ((tid & 63) == 0) { red[w] = s; red[4 + w] = ss; }
    __syncthreads();
    s  = red[0] + red[1] + red[2] + red[3];
    ss = red[4] + red[5] + red[6] + red[7];
    float mean = s * (1.f / 1024.f);
    float var  = ss * (1.f / 1024.f) - mean * mean;
    float inv  = rsqrtf(var + 1e-5f);
    #pragma unroll
    for (int i = 0; i < 4; i++) {
        int d = tid + 256 * i;
        float xn = (v[i] - mean) * inv;
        float y  = xn * ld1(lnw, d, isf32) + ld1(lnb, d, isf32);
        hin[(size_t)row * 1024 + d] = f2bf(y * (1.f + mb[4096 + d]) + mb[3072 + d]);
    }
}

// ---------------------------------------------------------------------------
// Legacy 64x64 GEMM kept ONLY for the no-weight-cache fallback path.
// ---------------------------------------------------------------------------
template <int EPI>
__global__ void __launch_bounds__(256) gemm_bt_kernel(
    const void* __restrict__ A, int lda,
    const void* __restrict__ W, int wrow0,
    const void* __restrict__ bias,
    void* __restrict__ Cout, int ldc, int K, int p0, int p1,
    int a_ext, int wmode, const int* __restrict__ dflag) {
    __shared__ ushort_t As[64][40];
    __shared__ ushort_t Bs[64][40];
    int isf32 = *dflag;
    int fa = a_ext ? isf32 : 0;
    int fw = (wmode == 2) ? 0 : isf32;
    int m0 = blockIdx.x * 64, n0 = blockIdx.y * 64;
    int tid = threadIdx.x;
    int r = tid >> 2, c = (tid & 3) * 8;
    int w = tid >> 6, ln = tid & 63;
    int msub = (w & 1) * 32, nsub = (w >> 1) * 32;
    int fr = ln & 15, q = ln >> 4;
    f32x4 acc00 = {0.f,0.f,0.f,0.f}, acc01 = {0.f,0.f,0.f,0.f};
    f32x4 acc10 = {0.f,0.f,0.f,0.f}, acc11 = {0.f,0.f,0.f,0.f};
    for (int k0 = 0; k0 < K; k0 += 32) {
        __syncthreads();
        {
            ushort_t t8[8];
            stage8(A, (size_t)(m0 + r) * lda + c + k0, fa, t8);
            *(uint4*)&As[r][c] = *(uint4*)t8;
        }
        {
            ushort_t t8[8];
            stage8(W, (size_t)(wrow0 + n0 + r) * K + c + k0, fw, t8);
            *(uint4*)&Bs[r][c] = *(uint4*)t8;
        }
        __syncthreads();
        bf16x8 a0 = *(const bf16x8*)&As[msub + fr][q * 8];
        bf16x8 a1 = *(const bf16x8*)&As[msub + 16 + fr][q * 8];
        bf16x8 b0 = *(const bf16x8*)&Bs[nsub + fr][q * 8];
        bf16x8 b1 = *(const bf16x8*)&Bs[nsub + 16 + fr][q * 8];
        acc00 = __builtin_amdgcn_mfma_f32_16x16x32_bf16(a0, b0, acc00, 0, 0, 0);
        acc01 = __builtin_amdgcn_mfma_f32_16x16x32_bf16(a0, b1, acc01, 0, 0, 0);
        acc10 = __builtin_amdgcn_mfma_f32_16x16x32_bf16(a1, b0, acc10, 0, 0, 0);
        acc11 = __builtin_amdgcn_mfma_f32_16x16x32_bf16(a1, b1, acc11, 0, 0, 0);
    }
    int col0 = n0 + nsub + fr;
    float bv0 = ld1(bias, wrow0 + col0, isf32);
    float bv1 = ld1(bias, wrow0 + col0 + 16, isf32);
    #pragma unroll
    for (int mi = 0; mi < 2; mi++) {
        #pragma unroll
        for (int ni = 0; ni < 2; ni++) {
            f32x4 a = (mi == 0) ? (ni == 0 ? acc00 : acc01) : (ni == 0 ? acc10 : acc11);
            int col = col0 + ni * 16;
            float bb = (ni == 0) ? bv0 : bv1;
            #pragma unroll
            for (int e = 0; e < 4; e++) {
                int rowg = m0 + msub + mi * 16 + q * 4 + e;
                float v = a[e] + bb;
                if (EPI == 2) v = gelu_exact(v);
                if (EPI == 0) {
                    ((float*)Cout)[(size_t)rowg * ldc + col] = v;
                } else if (EPI == 1 || EPI == 2) {
                    ((ushort_t*)Cout)[(size_t)rowg * ldc + col] = f2bf(v);
                } else if (EPI == 3) {
                    store_k((ushort_t*)Cout, rowg, col, p0, p1, v);
                } else if (EPI == 5) {
                    store_v((ushort_t*)Cout, rowg, col, p0, p1, v);
                } else {  // EPI == 4
                    store_q((ushort_t*)Cout, rowg, col, p0, v);
                }
            }
        }
    }
}

// ---------------------------------------------------------------------------
// Hybrid mainloops. BK=32 (16 KB LDS): best for occupancy-sensitive launches
// (stage1, 4.4 blocks/CU). BK=64 (32 KB LDS): best for grid-limited launches
// (qaout/o-proj/ffn1/ffn2 at <=2 blocks/CU) — halves barrier/drain per FLOP.
// ---------------------------------------------------------------------------
__device__ __forceinline__ void gemm_mainloop32(
    const ushort_t* __restrict__ A, int lda,
    const ushort_t* __restrict__ W, int ldw,
    int m0, int wrow0, int kbeg, int klen,
    ushort_t* As, ushort_t* Bs, f32x4 acc[4][4])
{
    const int tid = threadIdx.x;
    const int w = tid >> 6;
    const int ln = tid & 63;
    const int fr = ln & 15, q = ln >> 4;
    const int wm = w & 1, wn = w >> 1;
    const ushort_t* gA = A + (size_t)(m0 + (tid >> 2)) * lda + kbeg + (tid & 3) * 8;
    const ushort_t* gW = W + (size_t)(wrow0 + (tid >> 2)) * ldw + kbeg + (tid & 3) * 8;
    const size_t sA = (size_t)64 * lda;
    const size_t sW = (size_t)64 * ldw;
    ushort_t* lA = As + w * 512;
    ushort_t* lB = Bs + w * 512;
    for (int k = 0; k < klen; k += 32) {
        __syncthreads();
        gload16(gA, lA);
        gload16(gA + sA, lA + 2048);
        gload16(gW, lB);
        gload16(gW + sW, lB + 2048);
        gA += 32; gW += 32;
        __syncthreads();
        bf16x8 af[4], bfr[4];
        #pragma unroll
        for (int mi = 0; mi < 4; mi++)
            af[mi] = *(const bf16x8*)&As[(wm * 64 + mi * 16 + fr) * 32 + q * 8];
        #pragma unroll
        for (int ni = 0; ni < 4; ni++)
            bfr[ni] = *(const bf16x8*)&Bs[(wn * 64 + ni * 16 + fr) * 32 + q * 8];
        #pragma unroll
        for (int mi = 0; mi < 4; mi++)
            #pragma unroll
            for (int ni = 0; ni < 4; ni++)
                acc[mi][ni] = __builtin_amdgcn_mfma_f32_16x16x32_bf16(af[mi], bfr[ni], acc[mi][ni], 0, 0, 0);
    }
}

__device__ __forceinline__ void gemm_mainloop64(
    const ushort_t* __restrict__ A, int lda,
    const ushort_t* __restrict__ W, int ldw,
    int m0, int wrow0, int kbeg, int klen,
    ushort_t* As, ushort_t* Bs, f32x4 acc[4][4])
{
    const int tid = threadIdx.x;
    const int w = tid >> 6;
    const int ln = tid & 63;
    const int fr = ln & 15, q = ln >> 4;
    const int wm = w & 1, wn = w >> 1;
    const ushort_t* gA = A + (size_t)(m0 + (tid >> 2)) * lda + kbeg + (tid & 3) * 8;
    const ushort_t* gW = W + (size_t)(wrow0 + (tid >> 2)) * ldw + kbeg + (tid & 3) * 8;
    const size_t sA = (size_t)64 * lda;
    const size_t sW = (size_t)64 * ldw;
    ushort_t* lA = As + w * 512;
    ushort_t* lB = Bs + w * 512;
    for (int k = 0; k < klen; k += 64) {
        __syncthreads();
        gload16(gA, lA);                          // kk0: rows 0..63
        gload16(gA + sA, lA + 2048);              // kk0: rows 64..127
        gload16(gA + 32, lA + 4096);              // kk1: rows 0..63
        gload16(gA + sA + 32, lA + 6144);         // kk1: rows 64..127
        gload16(gW, lB);
        gload16(gW + sW, lB + 2048);
        gload16(gW + 32, lB + 4096);
        gload16(gW + sW + 32, lB + 6144);
        gA += 64; gW += 64;
        __syncthreads();
        #pragma unroll
        for (int kk = 0; kk < 2; kk++) {
            bf16x8 af[4], bfr[4];
            #pragma unroll
            for (int mi = 0; mi < 4; mi++)
                af[mi] = *(const bf16x8*)&As[kk * 4096 + (wm * 64 + mi * 16 + fr) * 32 + q * 8];
            #pragma unroll
            for (int ni = 0; ni < 4; ni++)
                bfr[ni] = *(const bf16x8*)&Bs[kk * 4096 + (wn * 64 + ni * 16 + fr) * 32 + q * 8];
            #pragma unroll
            for (int mi = 0; mi < 4; mi++)
                #pragma unroll
                for (int ni = 0; ni < 4; ni++)
                    acc[mi][ni] = __builtin_amdgcn_mfma_f32_16x16x32_bf16(af[mi], bfr[ni], acc[mi][ni], 0, 0, 0);
        }
    }
}

// ---------------------------------------------------------------------------
// Merged stage-1 GEMM (BK=32) with FUSED RMS-norm + RoPE epilogues.
// blocks 0..479: q_proj|qa|K0|V0 over xnorm; 480..1119: cross-source K/V.
// ---------------------------------------------------------------------------
__global__ void __launch_bounds__(256) gemm_stage1_kernel(
    const ushort_t* __restrict__ xnorm,
    const ushort_t* __restrict__ actA, const ushort_t* __restrict__ actB,
    const ushort_t* __restrict__ Wq, const ushort_t* __restrict__ Wqa,
    const ushort_t* __restrict__ Wk, const ushort_t* __restrict__ Wv,
    const void* __restrict__ bq, const void* __restrict__ bqa,
    const void* __restrict__ bk, const void* __restrict__ bv,
    const void* __restrict__ qnw, const void* __restrict__ knw,
    const float* __restrict__ ropetab,
    ushort_t* __restrict__ qbuf, ushort_t* __restrict__ qah,
    ushort_t* __restrict__ kbuf, ushort_t* __restrict__ vbufT,
    const int* __restrict__ dflag)
{
    __shared__ ushort_t As[4096], Bs[4096];
    int isf32 = *dflag;
    int bid = blockIdx.x;
    int mode, koff = 0, p1 = 9, srow0, wrow0, am0, boff = 0;
    const ushort_t* A;
    const ushort_t* W;
    const void* bias;
    if (bid < 480) {
        int bx = bid % 16, by = bid / 16;
        am0 = bx * 128; srow0 = am0;
        int n0 = by * 128;
        A = xnorm;
        if (n0 < 1024)      { mode = 0; W = Wq;  bias = bq;  wrow0 = n0; }
        else if (n0 < 1792) { mode = 1; W = Wqa; bias = bqa; wrow0 = n0 - 1024; }
        else if (n0 < 2816) { mode = 2; W = Wk;  bias = bk;  wrow0 = n0 - 1792; }
        else                { mode = 3; W = Wv;  bias = bv;  wrow0 = n0 - 2816; }
    } else {
        int id2 = bid - 480;               // 0..639
        int mb = id2 % 40, ny = id2 / 40;
        int src;
        if (mb < 16)      { src = 0; A = actA; am0 = mb * 128;        srow0 = am0;             koff = 512;  p1 = 9; }
        else if (mb < 32) { src = 1; A = actA; am0 = mb * 128;        srow0 = (mb - 16) * 128; koff = 1024; p1 = 9; }
        else              { src = 2; A = actB; am0 = (mb - 32) * 128; srow0 = am0;             koff = 1536; p1 = 8; }
        int n0 = ny * 128;
        int isK = (n0 < 1024);
        wrow0 = isK ? n0 : n0 - 1024;
        W = (isK ? Wk : Wv) + (size_t)(src + 1) * 1048576;
        bias = isK ? bk : bv;
        boff = (src + 1) * 1024;
        mode = isK ? 2 : 3;
    }
    f32x4 acc[4][4];
    #pragma unroll
    for (int i = 0; i < 4; i++)
        #pragma unroll
        for (int j = 0; j < 4; j++) acc[i][j] = (f32x4){0.f, 0.f, 0.f, 0.f};
    gemm_mainloop32(A, 1024, W, 1024, am0, wrow0, 0, 1024, As, Bs, acc);
    int tid = threadIdx.x, w = tid >> 6, ln = tid & 63;
    int fr = ln & 15, q = ln >> 4;
    int wm = w & 1, wn = w >> 1;
    float bb[4], nw[4];
    #pragma unroll
    for (int ni = 0; ni < 4; ni++)
        bb[ni] = ld1(bias, boff + wrow0 + wn * 64 + ni * 16 + fr, isf32);
    if (mode == 0 || mode == 2) {
        const void* nwp = (mode == 0) ? qnw : knw;
        #pragma unroll
        for (int ni = 0; ni < 4; ni++) nw[ni] = ld1(nwp, ni * 16 + fr, isf32);
    }
    const int tmask = (1 << p1) - 1;
    #pragma unroll
    for (int mi = 0; mi < 4; mi++) {
        #pragma unroll
        for (int e = 0; e < 4; e++) {
            int row = srow0 + wm * 64 + mi * 16 + q * 4 + e;
            float v0 = acc[mi][0][e] + bb[0];
            float v1 = acc[mi][1][e] + bb[1];
            float v2 = acc[mi][2][e] + bb[2];
            float v3 = acc[mi][3][e] + bb[3];
            int c0 = wrow0 + wn * 64 + fr;
            if (mode == 1) {
                qah[(size_t)row * 768 + c0]      = f2bf(v0);
                qah[(size_t)row * 768 + c0 + 16] = f2bf(v1);
                qah[(size_t)row * 768 + c0 + 32] = f2bf(v2);
                qah[(size_t)row * 768 + c0 + 48] = f2bf(v3);
            } else if (mode == 3) {
                store_v(vbufT, row, c0,      koff, p1, v0);
                store_v(vbufT, row, c0 + 16, koff, p1, v1);
                store_v(vbufT, row, c0 + 32, koff, p1, v2);
                store_v(vbufT, row, c0 + 48, koff, p1, v3);
            } else {
                float ss = v0*v0 + v1*v1 + v2*v2 + v3*v3;
                ss += __shfl_xor(ss, 1, 64);
                ss += __shfl_xor(ss, 2, 64);
                ss += __shfl_xor(ss, 4, 64);
                ss += __shfl_xor(ss, 8, 64);
                float inv = rsqrtf(ss * (1.f / 64.f) + 1e-6f);
                float y0 = v0 * inv * nw[0];
                float y1 = v1 * inv * nw[1];
                float y2 = v2 * inv * nw[2];
                float y3 = v3 * inv * nw[3];
                int t = row & tmask;
                float2 cs0 = *(const float2*)&ropetab[((t << 5) + fr) * 2];
                float2 cs1 = *(const float2*)&ropetab[((t << 5) + 16 + fr) * 2];
                float r0 = y0 * cs0.x - y2 * cs0.y;
                float r1 = y1 * cs1.x - y3 * cs1.y;
                float r2 = y2 * cs0.x + y0 * cs0.y;
                float r3 = y3 * cs1.x + y1 * cs1.y;
                if (mode == 0) {
                    store_q(qbuf, row, c0,      0, r0);
                    store_q(qbuf, row, c0 + 16, 0, r1);
                    store_q(qbuf, row, c0 + 32, 0, r2);
                    store_q(qbuf, row, c0 + 48, 0, r3);
                } else {
                    store_k(kbuf, row, c0,      koff, p1, r0);
                    store_k(kbuf, row, c0 + 16, koff, p1, r1);
                    store_k(kbuf, row, c0 + 32, koff, p1, r2);
                    store_k(kbuf, row, c0 + 48, koff, p1, r3);
                }
            }
        }
    }
}

// qa_out (BK=64) batched over blockIdx.z; FUSED RMS-norm (qn_w), no RoPE.
__global__ void __launch_bounds__(256) gemm_qaout_kernel(
    const ushort_t* __restrict__ qah,
    const ushort_t* __restrict__ W, const void* __restrict__ bias,
    const void* __restrict__ qnw,
    ushort_t* __restrict__ qbuf, const int* __restrict__ dflag)
{
    __shared__ ushort_t As[8192], Bs[8192];
    int isf32 = *dflag;
    int m0 = blockIdx.x * 128, n0 = blockIdx.y * 128;
    int z = blockIdx.z;
    const ushort_t* A = qah + (size_t)z * 256;
    f32x4 acc[4][4];
    #pragma unroll
    for (int i = 0; i < 4; i++)
        #pragma unroll
        for (int j = 0; j < 4; j++) acc[i][j] = (f32x4){0.f, 0.f, 0.f, 0.f};
    gemm_mainloop64(A, 768, W, 256, m0, n0, 0, 256, As, Bs, acc);
    int tid = threadIdx.x, w = tid >> 6, ln = tid & 63;
    int fr = ln & 15, q = ln >> 4, wm = w & 1, wn = w >> 1;
    float bb[4], nw[4];
    #pragma unroll
    for (int ni = 0; ni < 4; ni++) {
        bb[ni] = ld1(bias, n0 + wn * 64 + ni * 16 + fr, isf32);
        nw[ni] = ld1(qnw, ni * 16 + fr, isf32);
    }
    #pragma unroll
    for (int mi = 0; mi < 4; mi++) {
        #pragma unroll
        for (int e = 0; e < 4; e++) {
            int row = m0 + wm * 64 + mi * 16 + q * 4 + e;
            float v0 = acc[mi][0][e] + bb[0];
            float v1 = acc[mi][1][e] + bb[1];
            float v2 = acc[mi][2][e] + bb[2];
            float v3 = acc[mi][3][e] + bb[3];
            float ss = v0*v0 + v1*v1 + v2*v2 + v3*v3;
            ss += __shfl_xor(ss, 1, 64);
            ss += __shfl_xor(ss, 2, 64);
            ss += __shfl_xor(ss, 4, 64);
            ss += __shfl_xor(ss, 8, 64);
            float inv = rsqrtf(ss * (1.f / 64.f) + 1e-6f);
            int c0 = n0 + wn * 64 + fr;
            store_q(qbuf, row, c0,      1 + z, v0 * inv * nw[0]);
            store_q(qbuf, row, c0 + 16, 1 + z, v1 * inv * nw[1]);
            store_q(qbuf, row, c0 + 32, 1 + z, v2 * inv * nw[2]);
            store_q(qbuf, row, c0 + 48, 1 + z, v3 * inv * nw[3]);
        }
    }
}

// Plain GEMM (BK=64). EPI 0: f32 out, split-K partials via blockIdx.z -> o0..o3
// (bias only at z=0). EPI 2: gelu -> bf16 row-major to o0.
template <int EPI>
__global__ void __launch_bounds__(256) gemm_plain_kernel(
    const ushort_t* __restrict__ A, int lda,
    const ushort_t* __restrict__ W, int ldw,
    const void* __restrict__ bias,
    void* __restrict__ o0, void* __restrict__ o1,
    void* __restrict__ o2, void* __restrict__ o3,
    int ldc, int ksub, const int* __restrict__ dflag)
{
    __shared__ ushort_t As[8192], Bs[8192];
    int isf32 = *dflag;
    int m0 = blockIdx.x * 128, n0 = blockIdx.y * 128;
    int z = blockIdx.z;
    void* Cout = (z == 0) ? o0 : (z == 1) ? o1 : (z == 2) ? o2 : o3;
    f32x4 acc[4][4];
    #pragma unroll
    for (int i = 0; i < 4; i++)
        #pragma unroll
        for (int j = 0; j < 4; j++) acc[i][j] = (f32x4){0.f, 0.f, 0.f, 0.f};
    gemm_mainloop64(A, lda, W, ldw, m0, n0, z * ksub, ksub, As, Bs, acc);
    int tid = threadIdx.x, w = tid >> 6, ln = tid & 63;
    int fr = ln & 15, q = ln >> 4, wm = w & 1, wn = w >> 1;
    #pragma unroll
    for (int ni = 0; ni < 4; ni++) {
        int c = n0 + wn * 64 + ni * 16 + fr;
        float bb = (z == 0) ? ld1(bias, c, isf32) : 0.f;
        #pragma unroll
        for (int mi = 0; mi < 4; mi++) {
            #pragma unroll
            for (int e = 0; e < 4; e++) {
                int row = m0 + wm * 64 + mi * 16 + q * 4 + e;
                float v = acc[mi][ni][e] + bb;
                if (EPI == 2) {
                    ((ushort_t*)Cout)[(size_t)row * ldc + c] = f2bf(gelu_exact(v));
                } else {
                    ((float*)Cout)[(size_t)row * ldc + c] = v;
                }
            }
        }
    }
}

__global__ void __launch_bounds__(256) qrope_ip_kernel(
    ushort_t* __restrict__ qbuf, const void* __restrict__ qnw,
    const int* __restrict__ dflag) {
    int isf32 = *dflag;
    int w = threadIdx.x >> 6, ln = threadIdx.x & 63;
    int flat = blockIdx.x * 4 + w;
    int t = flat & 511, s = (flat >> 9) & 3;
    ushort_t* p = qbuf + (size_t)flat * 64;
    float x = bf2f(p[ln]);
    float ssum = x * x;
    #pragma unroll
    for (int off = 1; off < 64; off <<= 1) ssum += __shfl_xor(ssum, off, 64);
    float y = x * rsqrtf(ssum * (1.f / 64.f) + 1e-6f) * ld1(qnw, ln, isf32);
    if (s == 0) {
        float ang = (float)t * __expf(-(float)(ln & 31) * (9.210340371976184f / 32.f));
        float cs, sn;
        sincosf(ang, &sn, &cs);
        float other = __shfl_xor(y, 32, 64);
        y = y * cs + ((ln < 32) ? -other : other) * sn;
    }
    p[ln] = f2bf(y);
}

__global__ void __launch_bounds__(256) krope_ip_kernel(
    ushort_t* __restrict__ kbuf, const void* __restrict__ knw,
    const int* __restrict__ dflag) {
    int isf32 = *dflag;
    int w = threadIdx.x >> 6, ln = threadIdx.x & 63;
    int flat = blockIdx.x * 4 + w;
    int j = flat % 1792;
    int t = j & 511;
    ushort_t* p = kbuf + (size_t)flat * 64;
    float x = bf2f(p[ln]);
    float ssum = x * x;
    #pragma unroll
    for (int off = 1; off < 64; off <<= 1) ssum += __shfl_xor(ssum, off, 64);
    float y = x * rsqrtf(ssum * (1.f / 64.f) + 1e-6f) * ld1(knw, ln, isf32);
    float ang = (float)t * __expf(-(float)(ln & 31) * (9.210340371976184f / 32.f));
    float cs, sn;
    sincosf(ang, &sn, &cs);
    float other = __shfl_xor(y, 32, 64);
    y = y * cs + ((ln < 32) ? -other : other) * sn;
    p[ln] = f2bf(y);
}

// ---------------------------------------------------------------------------
// MFMA flash attention. Single-buffered K/V LDS (27.6 KB -> 5 blocks/CU),
// register prefetch, 2 barriers/tile, XCD-aware 1D swizzle.
// ---------------------------------------------------------------------------
__global__ void __launch_bounds__(256) attn_mfma_kernel(
    const ushort_t* __restrict__ qbuf, const ushort_t* __restrict__ kbuf,
    const ushort_t* __restrict__ vbufT, const float* __restrict__ consts,
    float* __restrict__ pacc0, float* __restrict__ pacc1,
    float* __restrict__ pml) {
    __shared__ ushort_t ks[64][72];
    __shared__ ushort_t vsT[64][72];
    __shared__ ushort_t ps[4][16][72];
    int id = blockIdx.x;
    int g  = (id & 7) | ((id >> 6) << 3);      // 0..127
    int qx = (id >> 3) & 7;
    int bh = g & 63;
    int z  = g >> 6;
    int tid = threadIdx.x, w = tid >> 6, ln = tid & 63;
    int r0 = qx * 64 + w * 16;
    int m = ln & 15, quad = ln >> 4;
    const int ntile = z ? 12 : 16;     // 8+8 or 8+4 64-key tiles
    const int keybase = z * 1024;
    const int s0i = z * 2;

    const ushort_t* qb = qbuf + (size_t)bh * 4 * 512 * 64;
    bf16x8 qA0f = *(const bf16x8*)(qb + ((size_t)(s0i * 512 + r0 + m)) * 64 + quad * 8);
    bf16x8 qA1f = *(const bf16x8*)(qb + ((size_t)(s0i * 512 + r0 + m)) * 64 + 32 + quad * 8);
    bf16x8 qB0f = *(const bf16x8*)(qb + ((size_t)((s0i + 1) * 512 + r0 + m)) * 64 + quad * 8);
    bf16x8 qB1f = *(const bf16x8*)(qb + ((size_t)((s0i + 1) * 512 + r0 + m)) * 64 + 32 + quad * 8);

    const float aA = consts[s0i],     bA = consts[4 + s0i];
    const float aB = consts[s0i + 1], bB = consts[4 + s0i + 1];

    float m_i[4], l_i[4];
    f32x4 acc[4];
    #pragma unroll
    for (int e = 0; e < 4; e++) { m_i[e] = -1e30f; l_i[e] = 0.f; }
    #pragma unroll
    for (int d = 0; d < 4; d++) acc[d] = (f32x4){0.f, 0.f, 0.f, 0.f};

    const ushort_t* kb  = kbuf  + (size_t)bh * 1792 * 64 + (size_t)keybase * 64;
    const ushort_t* vbT = vbufT + (size_t)bh * 64 * 1792 + keybase;
    int skey = tid >> 3, sd = (tid & 7) * 8;
    uint4 kreg0 = *(const uint4*)(kb + (size_t)skey * 64 + sd);
    uint4 kreg1 = *(const uint4*)(kb + (size_t)(skey + 32) * 64 + sd);
    uint4 vreg0 = *(const uint4*)(vbT + (size_t)skey * 1792 + sd);
    uint4 vreg1 = *(const uint4*)(vbT + (size_t)(skey + 32) * 1792 + sd);
    *(uint4*)&ks[skey][sd]       = kreg0;
    *(uint4*)&ks[skey + 32][sd]  = kreg1;
    *(uint4*)&vsT[skey][sd]      = vreg0;
    *(uint4*)&vsT[skey + 32][sd] = vreg1;
    __syncthreads();

    for (int ti = 0; ti < ntile; ti++) {
        const bool pf = (ti + 1 < ntile);
        if (pf) {                      // prefetch next 64-key tile into regs
            int nx = (ti + 1) * 64;
            kreg0 = *(const uint4*)(kb + (size_t)(nx + skey) * 64 + sd);
            kreg1 = *(const uint4*)(kb + (size_t)(nx + skey + 32) * 64 + sd);
            vreg0 = *(const uint4*)(vbT + (size_t)skey * 1792 + nx + sd);
            vreg1 = *(const uint4*)(vbT + (size_t)(skey + 32) * 1792 + nx + sd);
        }
        int sl = (ti >= 8) ? 1 : 0;
        float a_s = sl ? aB : aA;
        float b_s = sl ? bB : bA;
        bf16x8 qA0 = sl ? qB0f : qA0f;
        bf16x8 qA1 = sl ? qB1f : qA1f;
        // QK^T: S[16q x 64key] as four C-frags
        f32x4 zero = {0.f, 0.f, 0.f, 0.f};
        bf16x8 k0a = *(const bf16x8*)&ks[m][quad * 8];
        bf16x8 k0b = *(const bf16x8*)&ks[m][32 + quad * 8];
        bf16x8 k1a = *(const bf16x8*)&ks[16 + m][quad * 8];
        bf16x8 k1b = *(const bf16x8*)&ks[16 + m][32 + quad * 8];
        bf16x8 k2a = *(const bf16x8*)&ks[32 + m][quad * 8];
        bf16x8 k2b = *(const bf16x8*)&ks[32 + m][32 + quad * 8];
        bf16x8 k3a = *(const bf16x8*)&ks[48 + m][quad * 8];
        bf16x8 k3b = *(const bf16x8*)&ks[48 + m][32 + quad * 8];
        f32x4 sc0 = __builtin_amdgcn_mfma_f32_16x16x32_bf16(qA0, k0a, zero, 0, 0, 0);
        sc0 = __builtin_amdgcn_mfma_f32_16x16x32_bf16(qA1, k0b, sc0, 0, 0, 0);
        f32x4 sc1 = __builtin_amdgcn_mfma_f32_16x16x32_bf16(qA0, k1a, zero, 0, 0, 0);
        sc1 = __builtin_amdgcn_mfma_f32_16x16x32_bf16(qA1, k1b, sc1, 0, 0, 0);
        f32x4 sc2 = __builtin_amdgcn_mfma_f32_16x16x32_bf16(qA0, k2a, zero, 0, 0, 0);
        sc2 = __builtin_amdgcn_mfma_f32_16x16x32_bf16(qA1, k2b, sc2, 0, 0, 0);
        f32x4 sc3 = __builtin_amdgcn_mfma_f32_16x16x32_bf16(qA0, k3a, zero, 0, 0, 0);
        sc3 = __builtin_amdgcn_mfma_f32_16x16x32_bf16(qA1, k3b, sc3, 0, 0, 0);
        // online softmax per row: max reduce across 16 m-lanes; l kept as
        // per-lane partial; rescale only when running max grows > 8 (T13).
        #pragma unroll
        for (int e = 0; e < 4; e++) {
            float s0 = sc0[e] * a_s + b_s;
            float s1 = sc1[e] * a_s + b_s;
            float s2 = sc2[e] * a_s + b_s;
            float s3 = sc3[e] * a_s + b_s;
            float mxe = fmaxf(fmaxf(s0, s1), fmaxf(s2, s3));
            #pragma unroll
            for (int off = 1; off < 16; off <<= 1) mxe = fmaxf(mxe, __shfl_xor(mxe, off, 64));
            if (mxe > m_i[e] + 8.f) {
                float alpha = __expf(m_i[e] - mxe);
                m_i[e] = mxe;
                l_i[e] *= alpha;
                acc[0][e] *= alpha; acc[1][e] *= alpha;
                acc[2][e] *= alpha; acc[3][e] *= alpha;
            }
            float p0 = __expf(s0 - m_i[e]), p1 = __expf(s1 - m_i[e]);
            float p2 = __expf(s2 - m_i[e]), p3 = __expf(s3 - m_i[e]);
            l_i[e] += (p0 + p1) + (p2 + p3);
            int row = quad * 4 + e;
            ps[w][row][m]      = f2bf(p0);
            ps[w][row][m + 16] = f2bf(p1);
            ps[w][row][m + 32] = f2bf(p2);
            ps[w][row][m + 48] = f2bf(p3);
        }
        // PV: per-wave ps, intra-wave lgkmcnt ordering suffices
        bf16x8 pA0 = *(const bf16x8*)&ps[w][m][quad * 8];
        bf16x8 pA1 = *(const bf16x8*)&ps[w][m][32 + quad * 8];
        #pragma unroll
        for (int dsub = 0; dsub < 4; dsub++) {
            bf16x8 vB0 = *(const bf16x8*)&vsT[dsub * 16 + m][quad * 8];
            bf16x8 vB1 = *(const bf16x8*)&vsT[dsub * 16 + m][32 + quad * 8];
            acc[dsub] = __builtin_amdgcn_mfma_f32_16x16x32_bf16(pA0, vB0, acc[dsub], 0, 0, 0);
            acc[dsub] = __builtin_amdgcn_mfma_f32_16x16x32_bf16(pA1, vB1, acc[dsub], 0, 0, 0);
        }
        if (pf) {
            __syncthreads();           // all waves done reading ks/vsT
            *(uint4*)&ks[skey][sd]       = kreg0;
            *(uint4*)&ks[skey + 32][sd]  = kreg1;
            *(uint4*)&vsT[skey][sd]      = vreg0;
            *(uint4*)&vsT[skey + 32][sd] = vreg1;
            __syncthreads();           // next tile visible
        }
    }
    // reduce per-lane l partials across the 16 m-lanes of each row
    #pragma unroll
    for (int e = 0; e < 4; e++) {
        float l = l_i[e];
        #pragma unroll
        for (int off = 1; off < 16; off <<= 1) l += __shfl_xor(l, off, 64);
        l_i[e] = l;
    }
    float* pacc = z ? pacc1 : pacc0;
    #pragma unroll
    for (int e = 0; e < 4; e++) {
        int t = r0 + quad * 4 + e;
        if (m == 0) {
            size_t mi = (((size_t)z * 64 + bh) * 512 + t) * 2;
            pml[mi]     = m_i[e];
            pml[mi + 1] = l_i[e];
        }
        #pragma unroll
        for (int dsub = 0; dsub < 4; dsub++) {
            pacc[((size_t)bh * 512 + t) * 64 + dsub * 16 + m] = acc[dsub][e];
        }
    }
}

__global__ void __launch_bounds__(256) attn_combine_kernel(
    const float* __restrict__ pacc0, const float* __restrict__ pacc1,
    const float* __restrict__ pml, ushort_t* __restrict__ attn_out) {
    int tid = threadIdx.x, w = tid >> 6, ln = tid & 63;
    int idx = blockIdx.x * 4 + w;           // 0..32767 = bh*512 + t
    int bh = idx >> 9, t = idx & 511;
    int b = bh >> 4, h = bh & 15;
    size_t r = (size_t)bh * 512 + t;
    float m0 = pml[r * 2],                 l0 = pml[r * 2 + 1];
    float m1 = pml[((size_t)32768 + r) * 2], l1 = pml[((size_t)32768 + r) * 2 + 1];
    float M = fmaxf(m0, m1);
    float w0 = __expf(m0 - M), w1 = __expf(m1 - M);
    float inv = 1.f / (l0 * w0 + l1 * w1);
    float a0 = pacc0[r * 64 + ln];
    float a1 = pacc1[r * 64 + ln];
    attn_out[(((size_t)(b * 512 + t)) * 16 + h) * 64 + ln] = f2bf((a0 * w0 + a1 * w1) * inv);
}

// ---------------------------------------------------------------------------
// Legacy full-key attention (fallback path only).
// ---------------------------------------------------------------------------
__global__ void __launch_bounds__(256) attn_mfma_legacy_kernel(
    const ushort_t* __restrict__ qbuf, const ushort_t* __restrict__ kbuf,
    const ushort_t* __restrict__ vbufT, const float* __restrict__ consts,
    ushort_t* __restrict__ attn_out) {
    __shared__ ushort_t ks[2][64][72];
    __shared__ ushort_t vsT[2][64][72];
    __shared__ ushort_t ps[4][16][72];
    int bh = blockIdx.y;
    int b = bh >> 4, h = bh & 15;
    int tid = threadIdx.x, w = tid >> 6, ln = tid & 63;
    int r0 = blockIdx.x * 64 + w * 16;
    int m = ln & 15, quad = ln >> 4;
    const ushort_t* qb = qbuf + (size_t)bh * 4 * 512 * 64;
    bf16x8 qf[4][2];
    #pragma unroll
    for (int s = 0; s < 4; s++) {
        qf[s][0] = *(const bf16x8*)(qb + ((size_t)(s * 512 + r0 + m)) * 64 + quad * 8);
        qf[s][1] = *(const bf16x8*)(qb + ((size_t)(s * 512 + r0 + m)) * 64 + 32 + quad * 8);
    }
    float m_i[4], l_i[4];
    f32x4 acc[4];
    #pragma unroll
    for (int e = 0; e < 4; e++) { m_i[e] = -1e30f; l_i[e] = 0.f; }
    #pragma unroll
    for (int d = 0; d < 4; d++) acc[d] = (f32x4){0.f, 0.f, 0.f, 0.f};
    const ushort_t* kb  = kbuf  + (size_t)bh * 1792 * 64;
    const ushort_t* vbT = vbufT + (size_t)bh * 64 * 1792;
    int skey = tid >> 3, sd = (tid & 7) * 8;
    uint4 kreg0 = *(const uint4*)(kb + (size_t)skey * 64 + sd);
    uint4 kreg1 = *(const uint4*)(kb + (size_t)(skey + 32) * 64 + sd);
    uint4 vreg0 = *(const uint4*)(vbT + (size_t)skey * 1792 + sd);
    uint4 vreg1 = *(const uint4*)(vbT + (size_t)(skey + 32) * 1792 + sd);
    *(uint4*)&ks[0][skey][sd]       = kreg0;
    *(uint4*)&ks[0][skey + 32][sd]  = kreg1;
    *(uint4*)&vsT[0][skey][sd]      = vreg0;
    *(uint4*)&vsT[0][skey + 32][sd] = vreg1;
    __syncthreads();
    int tcnt = 0, p = 0;
    #pragma unroll
    for (int s = 0; s < 4; s++) {
        const float a_s = consts[s];
        const float b_s = consts[4 + s];
        const bf16x8 qA0 = qf[s][0];
        const bf16x8 qA1 = qf[s][1];
        const int NT = (s == 3) ? 4 : 8;
        for (int ti = 0; ti < NT; ti++) {
            if (tcnt < 27) {
                int nx = (tcnt + 1) * 64;
                kreg0 = *(const uint4*)(kb + (size_t)(nx + skey) * 64 + sd);
                kreg1 = *(const uint4*)(kb + (size_t)(nx + skey + 32) * 64 + sd);
                vreg0 = *(const uint4*)(vbT + (size_t)skey * 1792 + nx + sd);
                vreg1 = *(const uint4*)(vbT + (size_t)(skey + 32) * 1792 + nx + sd);
            }
            f32x4 zero = {0.f, 0.f, 0.f, 0.f};
            bf16x8 k0a = *(const bf16x8*)&ks[p][m][quad * 8];
            bf16x8 k0b = *(const bf16x8*)&ks[p][m][32 + quad * 8];
            bf16x8 k1a = *(const bf16x8*)&ks[p][16 + m][quad * 8];
            bf16x8 k1b = *(const bf16x8*)&ks[p][16 + m][32 + quad * 8];
            bf16x8 k2a = *(const bf16x8*)&ks[p][32 + m][quad * 8];
            bf16x8 k2b = *(const bf16x8*)&ks[p][32 + m][32 + quad * 8];
            bf16x8 k3a = *(const bf16x8*)&ks[p][48 + m][quad * 8];
            bf16x8 k3b = *(const bf16x8*)&ks[p][48 + m][32 + quad * 8];
            f32x4 sc0 = __builtin_amdgcn_mfma_f32_16x16x32_bf16(qA0, k0a, zero, 0, 0, 0);
            sc0 = __builtin_amdgcn_mfma_f32_16x16x32_bf16(qA1, k0b, sc0, 0, 0, 0);
            f32x4 sc1 = __builtin_amdgcn_mfma_f32_16x16x32_bf16(qA0, k1a, zero, 0, 0, 0);
            sc1 = __builtin_amdgcn_mfma_f32_16x16x32_bf16(qA1, k1b, sc1, 0, 0, 0);
            f32x4 sc2 = __builtin_amdgcn_mfma_f32_16x16x32_bf16(qA0, k2a, zero, 0, 0, 0);
            sc2 = __builtin_amdgcn_mfma_f32_16x16x32_bf16(qA1, k2b, sc2, 0, 0, 0);
            f32x4 sc3 = __builtin_amdgcn_mfma_f32_16x16x32_bf16(qA0, k3a, zero, 0, 0, 0);
            sc3 = __builtin_amdgcn_mfma_f32_16x16x32_bf16(qA1, k3b, sc3, 0, 0, 0);
            #pragma unroll
            for (int e = 0; e < 4; e++) {
                float s0 = sc0[e] * a_s + b_s;
                float s1 = sc1[e] * a_s + b_s;
                float s2 = sc2[e] * a_s + b_s;
                float s3 = sc3[e] * a_s + b_s;
                float mxe = fmaxf(fmaxf(s0, s1), fmaxf(s2, s3));
                #pragma unroll
                for (int off = 1; off < 16; off <<= 1) mxe = fmaxf(mxe, __shfl_xor(mxe, off, 64));
                if (mxe > m_i[e] + 8.f) {
                    float alpha = __expf(m_i[e] - mxe);
                    m_i[e] = mxe;
                    l_i[e] *= alpha;
                    acc[0][e] *= alpha; acc[1][e] *= alpha;
                    acc[2][e] *= alpha; acc[3][e] *= alpha;
                }
                float p0 = __expf(s0 - m_i[e]), p1 = __expf(s1 - m_i[e]);
                float p2 = __expf(s2 - m_i[e]), p3 = __expf(s3 - m_i[e]);
                l_i[e] += (p0 + p1) + (p2 + p3);
                int row = quad * 4 + e;
                ps[w][row][m]      = f2bf(p0);
                ps[w][row][m + 16] = f2bf(p1);
                ps[w][row][m + 32] = f2bf(p2);
                ps[w][row][m + 48] = f2bf(p3);
            }
            bf16x8 pA0 = *(const bf16x8*)&ps[w][m][quad * 8];
            bf16x8 pA1 = *(const bf16x8*)&ps[w][m][32 + quad * 8];
            #pragma unroll
            for (int dsub = 0; dsub < 4; dsub++) {
                bf16x8 vB0 = *(const bf16x8*)&vsT[p][dsub * 16 + m][quad * 8];
                bf16x8 vB1 = *(const bf16x8*)&vsT[p][dsub * 16 + m][32 + quad * 8];
                acc[dsub] = __builtin_amdgcn_mfma_f32_16x16x32_bf16(pA0, vB0, acc[dsub], 0, 0, 0);
                acc[dsub] = __builtin_amdgcn_mfma_f32_16x16x32_bf16(pA1, vB1, acc[dsub], 0, 0, 0);
            }
            if (tcnt < 27) {
                *(uint4*)&ks[1 - p][skey][sd]       = kreg0;
                *(uint4*)&ks[1 - p][skey + 32][sd]  = kreg1;
                *(uint4*)&vsT[1 - p][skey][sd]      = vreg0;
                *(uint4*)&vsT[1 - p][skey + 32][sd] = vreg1;
            }
            __syncthreads();
            p ^= 1;
            tcnt++;
        }
    }
    #pragma unroll
    for (int e = 0; e < 4; e++) {
        float l = l_i[e];
        #pragma unroll
        for (int off = 1; off < 16; off <<= 1) l += __shfl_xor(l, off, 64);
        float invl = 1.f / l;
        int t = r0 + quad * 4 + e;
        #pragma unroll
        for (int dsub = 0; dsub < 4; dsub++) {
            int d = dsub * 16 + m;
            attn_out[(((size_t)(b * 512 + t)) * 16 + h) * 64 + d] = f2bf(acc[dsub][e] * invl);
        }
    }
}

__global__ void resgate_kernel(const void* __restrict__ x, const float* __restrict__ p0,
                               const float* __restrict__ p1, const float* __restrict__ p2,
                               const float* __restrict__ p3,
                               const float* __restrict__ mod, float* __restrict__ x1,
                               int sum4, const int* __restrict__ dflag) {
    int isf32 = *dflag;
    int i = blockIdx.x * 256 + threadIdx.x;
    int b = i >> 19, n = i & 1023;
    float proj = p0[i];
    if (sum4) proj += p1[i] + p2[i] + p3[i];
    x1[i] = ld1(x, i, isf32) + mod[(size_t)b * 6144 + 2048 + n] * proj;
}
__global__ void final_kernel(const float* __restrict__ x1, const float* __restrict__ f0,
                             const float* __restrict__ f1, const float* __restrict__ f2,
                             const float* __restrict__ f3,
                             const float* __restrict__ mod, void* __restrict__ out,
                             int sum4, const int* __restrict__ dflag) {
    int isf32 = *dflag;
    int i = blockIdx.x * 256 + threadIdx.x;
    int b = i >> 19, n = i & 1023;
    float ffn = f0[i];
    if (sum4) ffn += f1[i] + f2[i] + f3[i];
    float val = x1[i] + mod[(size_t)b * 6144 + 5120 + n] * ffn;
    if (isf32) ((float*)out)[i] = val;
    else       ((ushort_t*)out)[i] = f2bf(val);
}

static constexpr size_t OFF_CONSTS   = 0;
static constexpr size_t OFF_FLAG     = 64;
static constexpr size_t OFF_MOD      = 512;
static constexpr size_t OFF_XNORM    = OFF_MOD    + 98304;      // 98816
static constexpr size_t OFF_QAH      = OFF_XNORM  + 4194304;
static constexpr size_t OFF_KBUF     = OFF_XNORM  + 8388608;    // 8487424
static constexpr size_t OFF_VBUF     = OFF_KBUF   + 14680064;   // 23167488
static constexpr size_t OFF_QBUF     = OFF_VBUF   + 14680064;   // 37847552
static constexpr size_t OFF_ATTNOUT  = OFF_QBUF   + 16777216;   // 54624768
static constexpr size_t OFF_WCACHE   = OFF_ATTNOUT + 4194304;   // 58819072
static constexpr size_t OFF_PACC1    = OFF_WCACHE + CW_TOTAL * 2;   // 98664960
static constexpr size_t OFF_PML      = OFF_PACC1  + 8388608;        // 107053568
static constexpr size_t OFF_ROPE     = OFF_PML    + 524288;         // 107577856 (+131072)
static constexpr size_t WS_NEED      = OFF_WCACHE + 52428800;   // unchanged, known-good

extern "C" void kernel_launch(void* const* d_in, const int* in_sizes, int n_in,
                              void* d_out, int out_size, void* d_ws, size_t ws_size,
                              hipStream_t stream) {
    (void)in_sizes; (void)n_in; (void)out_size;
    const void* x        = d_in[0];
    const void* bev      = d_in[1];
    const void* vl       = d_in[2];
    const void* reas     = d_in[3];
    const void* cond     = d_in[4];
    const void* ln_pre_w = d_in[5];
    const void* ln_pre_b = d_in[6];
    const void* adaln_w  = d_in[7];
    const void* adaln_b  = d_in[8];
    const void* q_proj_w = d_in[9];
    const void* q_proj_b = d_in[10];
    const void* qa_w     = d_in[11];
    const void* qa_b     = d_in[12];
    const void* qa_out_w = d_in[13];
    const void* qa_out_b = d_in[14];
    const void* k_w      = d_in[15];
    const void* k_b      = d_in[16];
    const void* v_w      = d_in[17];
    const void* v_b      = d_in[18];
    const void* o_w      = d_in[19];
    const void* o_b      = d_in[20];
    const void* qn_w     = d_in[21];
    const void* kn_w     = d_in[22];
    const void* gating   = d_in[23];
    const void* temps    = d_in[24];
    const void* sbias    = d_in[25];
    const void* ffn_ln_w = d_in[26];
    const void* ffn_ln_b = d_in[27];
    const void* ffn_w1   = d_in[28];
    const void* ffn_b1   = d_in[29];
    const void* ffn_w2   = d_in[30];
    const void* ffn_b2   = d_in[31];

    char* ws = (char*)d_ws;
    float*    consts   = (float*)(ws + OFF_CONSTS);
    int*      dflag    = (int*)(ws + OFF_FLAG);
    float*    mod      = (float*)(ws + OFF_MOD);
    ushort_t* xnorm    = (ushort_t*)(ws + OFF_XNORM);
    ushort_t* qah      = (ushort_t*)(ws + OFF_QAH);
    ushort_t* kbuf     = (ushort_t*)(ws + OFF_KBUF);
    ushort_t* vbufT    = (ushort_t*)(ws + OFF_VBUF);
    ushort_t* qbuf     = (ushort_t*)(ws + OFF_QBUF);
    ushort_t* attnout  = (ushort_t*)(ws + OFF_ATTNOUT);
    float*    x1       = (float*)(ws + OFF_XNORM);
    ushort_t* hmid     = (ushort_t*)(ws + OFF_KBUF);
    ushort_t* hin      = (ushort_t*)(ws + OFF_ATTNOUT);
    ushort_t* wc       = (ushort_t*)(ws + OFF_WCACHE);
    float*    ropetab  = (float*)(ws + OFF_ROPE);
    // attention partials / staged activations
    float*    pacc0    = (float*)(ws + OFF_XNORM);               // xnorm+qah dead by attn
    float*    pacc1    = (float*)(ws + OFF_PACC1);
    float*    pml      = (float*)(ws + OFF_PML);
    ushort_t* actA     = (ushort_t*)(ws + OFF_PACC1);            // bev+vl bf16 (pre-attn)
    ushort_t* actB     = (ushort_t*)(ws + OFF_ATTNOUT);          // reas bf16 (pre-attn)
    // o-proj split-K partials (kbuf/vbuf/qbuf dead after attention)
    float*    op0      = (float*)(ws + OFF_KBUF);
    float*    op1      = (float*)(ws + OFF_KBUF + 8388608);
    float*    op2      = (float*)(ws + OFF_KBUF + 16777216);
    float*    op3      = (float*)(ws + OFF_QBUF);
    // ffn2 split-K partials (hmid occupies OFF_KBUF..+16M, keep clear of it)
    float*    f0       = (float*)(ws + OFF_QBUF);
    float*    f1       = (float*)(ws + OFF_QBUF + 8388608);
    float*    f2       = (float*)(ws + OFF_KBUF + 16777216);
    float*    f3       = (float*)(ws + OFF_PACC1);

    const bool use_cache = (ws_size >= WS_NEED);

    detect_kernel<<<1, 64, 0, stream>>>((const unsigned int*)x, dflag);
    prep_consts_kernel<<<1, 64, 0, stream>>>(temps, sbias, gating, consts, dflag);

    if (use_cache) {
        prep_rope_kernel<<<64, 256, 0, stream>>>(ropetab);
        convert_weights_kernel<<<9728, 256, 0, stream>>>(
            q_proj_w, qa_w, qa_out_w, k_w, v_w, o_w, ffn_w1, ffn_w2, wc, dflag);
        convert_act3_kernel<<<2560, 256, 0, stream>>>(bev, vl, reas, actA, actB, dflag);
        adaln_init_kernel<<<24, 256, 0, stream>>>(adaln_b, mod, dflag);
        adaln_kernel<<<dim3(24, 4, 4), 256, 0, stream>>>(cond, adaln_w, mod, dflag);
        ln_mod_kernel<0><<<2048, 256, 0, stream>>>(x, mod, ln_pre_w, ln_pre_b, 0, 1024, xnorm, dflag);

        // Merged stage-1 with fused RMS+RoPE epilogues (1120 blocks, BK=32)
        gemm_stage1_kernel<<<1120, 256, 0, stream>>>(
            xnorm, actA, actB,
            wc + CW_QPROJ, wc + CW_QA, wc + CW_KW, wc + CW_VW,
            q_proj_b, qa_b, k_b, v_b, qn_w, kn_w, ropetab,
            qbuf, qah, kbuf, vbufT, dflag);
        // qa_out x3 with fused RMS (qn_w), no rope (adapters) — BK=64
        gemm_qaout_kernel<<<dim3(16, 8, 3), 256, 0, stream>>>(
            qah, wc + CW_QAOUT, qa_out_b, qn_w, qbuf, dflag);

        attn_mfma_kernel<<<1024, 256, 0, stream>>>(
            qbuf, kbuf, vbufT, consts, pacc0, pacc1, pml);
        attn_combine_kernel<<<8192, 256, 0, stream>>>(pacc0, pacc1, pml, attnout);

        // o-proj split-K=4 (512 blocks, BK=64)
        gemm_plain_kernel<0><<<dim3(16, 8, 4), 256, 0, stream>>>(
            attnout, 1024, wc + CW_OW, 1024, o_b, op0, op1, op2, op3, 1024, 256, dflag);
        // fused residual-gate + FFN LayerNorm (writes x1 f32 + hin bf16)
        resgate_ln_kernel<<<2048, 256, 0, stream>>>(
            x, op0, op1, op2, op3, mod, ffn_ln_w, ffn_ln_b, x1, hin, dflag);
        gemm_plain_kernel<2><<<dim3(16, 32, 1), 256, 0, stream>>>(
            hin, 1024, wc + CW_FFN1, 1024, ffn_b1, hmid, nullptr, nullptr, nullptr, 4096, 1024, dflag);
        // ffn2 split-K=4 (512 blocks, BK=64)
        gemm_plain_kernel<0><<<dim3(16, 8, 4), 256, 0, stream>>>(
            hmid, 4096, wc + CW_FFN2, 4096, ffn_b2, f0, f1, f2, f3, 1024, 1024, dflag);
        final_kernel<<<8192, 256, 0, stream>>>(x1, f0, f1, f2, f3, mod, d_out, 1, dflag);
    } else {
        // Fallback: legacy 64x64 path reading original weights directly.
        float* proj0L = (float*)(ws + OFF_QBUF);
        adaln_init_kernel<<<24, 256, 0, stream>>>(adaln_b, mod, dflag);
        adaln_kernel<<<dim3(24, 4, 4), 256, 0, stream>>>(cond, adaln_w, mod, dflag);
        ln_mod_kernel<0><<<2048, 256, 0, stream>>>(x, mod, ln_pre_w, ln_pre_b, 0, 1024, xnorm, dflag);
        gemm_bt_kernel<4><<<dim3(32, 16), 256, 0, stream>>>(xnorm, 1024, q_proj_w, 0, q_proj_b, qbuf, 0, 1024, 0, 9, 0, 0, dflag);
        {
            const void* srcs[4] = {xnorm, bev, vl, reas};
            const int koffs[4] = {0, 512, 1024, 1536};
            const int p1s[4]   = {9, 9, 9, 8};
            for (int i = 0; i < 4; i++) {
                int aext = (i == 0) ? 0 : 1;
                int gx = (i == 3) ? 16 : 32;
                gemm_bt_kernel<3><<<dim3(gx, 16), 256, 0, stream>>>(
                    srcs[i], 1024, k_w, i * 1024, k_b, kbuf, 0, 1024, koffs[i], p1s[i], aext, 0, dflag);
                gemm_bt_kernel<5><<<dim3(gx, 16), 256, 0, stream>>>(
                    srcs[i], 1024, v_w, i * 1024, v_b, vbufT, 0, 1024, koffs[i], p1s[i], aext, 0, dflag);
            }
        }
        gemm_bt_kernel<1><<<dim3(32, 12), 256, 0, stream>>>(xnorm, 1024, qa_w, 0, qa_b, qah, 768, 1024, 0, 0, 0, 0, dflag);
        for (int i = 0; i < 3; i++)
            gemm_bt_kernel<4><<<dim3(32, 16), 256, 0, stream>>>(qah + i * 256, 768, qa_out_w, 0, qa_out_b,
                                                                qbuf, 0, 256, 1 + i, 9, 0, 0, dflag);
        qrope_ip_kernel<<<32768, 256, 0, stream>>>(qbuf, qn_w, dflag);
        krope_ip_kernel<<<28672, 256, 0, stream>>>(kbuf, kn_w, dflag);
        attn_mfma_legacy_kernel<<<dim3(8, 64), 256, 0, stream>>>(qbuf, kbuf, vbufT, consts, attnout);
        gemm_bt_kernel<0><<<dim3(32, 16), 256, 0, stream>>>(attnout, 1024, o_w, 0, o_b, proj0L, 1024, 1024, 0, 0, 0, 0, dflag);
        resgate_kernel<<<8192, 256, 0, stream>>>(x, proj0L, proj0L, proj0L, proj0L, mod, x1, 0, dflag);
        ln_mod_kernel<1><<<2048, 256, 0, stream>>>(x1, mod, ffn_ln_w, ffn_ln_b, 3072, 4096, hin, dflag);
        gemm_bt_kernel<2><<<dim3(32, 64), 256, 0, stream>>>(hin, 1024, ffn_w1, 0, ffn_b1, hmid, 4096, 1024, 0, 0, 0, 0, dflag);
        gemm_bt_kernel<0><<<dim3(32, 16), 256, 0, stream>>>(hmid, 4096, ffn_w2, 0, ffn_b2, proj0L, 1024, 4096, 0, 0, 0, 0, dflag);
        final_kernel<<<8192, 256, 0, stream>>>(x1, proj0L, proj0L, proj0L, proj0L, mod, d_out, 0, dflag);
    }
}